// Round 1
// baseline (10935.227 us; speedup 1.0000x reference)
//
#include <hip/hip_runtime.h>
#include <math.h>

// ---------------------------------------------------------------------------
// WaveletNet forward, fp32 direct implementation.
// N=16 fixed. Layout NCHW throughout.
// ---------------------------------------------------------------------------

#define NB 16  // batch

// ---------------- weight standardization ----------------
// one block per output filter; fan = Cin*KH*KW
__global__ void ws_kernel(const float* __restrict__ w, float* __restrict__ out, int fan) {
  __shared__ float red[512];
  int o = blockIdx.x;
  const float* wp = w + (size_t)o * fan;
  float s = 0.f, s2 = 0.f;
  for (int i = threadIdx.x; i < fan; i += 256) { float v = wp[i]; s += v; s2 += v * v; }
  red[threadIdx.x] = s; red[256 + threadIdx.x] = s2;
  __syncthreads();
  for (int st = 128; st > 0; st >>= 1) {
    if (threadIdx.x < st) {
      red[threadIdx.x] += red[threadIdx.x + st];
      red[256 + threadIdx.x] += red[256 + threadIdx.x + st];
    }
    __syncthreads();
  }
  float sum = red[0], sumsq = red[256];
  float mean = sum / (float)fan;
  float var = (sumsq - sum * mean) / (float)(fan - 1);  // unbiased (ddof=1)
  if (var < 0.f) var = 0.f;
  float inv = 1.0f / (sqrtf(var) + 1e-5f);
  for (int i = threadIdx.x; i < fan; i += 256)
    out[(size_t)o * fan + i] = (wp[i] - mean) * inv;
}

// ---------------- Haar forward (wt) ----------------
// in (N,C,2Ho,2Wo) -> out (N,4C,Ho,Wo); channel layout c*4+k; detail remap (r+1)/2
__global__ void wt_kernel(const float* __restrict__ in, float* __restrict__ out,
                          int C, int Ho, int Wo, int total) {
  int idx = blockIdx.x * 256 + threadIdx.x;
  if (idx >= total) return;
  int w = idx % Wo; int t = idx / Wo;
  int h = t % Ho; t /= Ho;
  int c = t % C; int n = t / C;
  int Wi = 2 * Wo;
  const float* ip = in + (((size_t)n * C + c) * (2 * Ho) + 2 * h) * Wi + 2 * w;
  float a = ip[0], b = ip[1], cc = ip[Wi], d = ip[Wi + 1];
  size_t cs = (size_t)Ho * Wo;
  float* op = out + (((size_t)n * 4 * C + 4 * c) * Ho + h) * Wo + w;
  op[0]      = 0.25f * (a + b + cc + d);
  op[cs]     = 0.25f * (a + b - cc - d) + 0.5f;
  op[2 * cs] = 0.25f * (a - b + cc - d) + 0.5f;
  op[3 * cs] = 0.25f * (a - b - cc + d) + 0.5f;
}

// ---------------- Haar inverse (iwt) ----------------
// v (N,4C,H,W) -> out region (N,Ctot,2H,2W) channels [c_off, c_off+C)
// detail un-map 2v-1; stride-2 k=2 transpose conv == disjoint 2x2 scatter
__global__ void iwt_kernel(const float* __restrict__ v, float* __restrict__ out,
                           int C, int H, int W, int c_off, int Ctot, int total) {
  int idx = blockIdx.x * 256 + threadIdx.x;
  if (idx >= total) return;  // total = N*C*H*W
  int w = idx % W; int t = idx / W;
  int h = t % H; t /= H;
  int c = t % C; int n = t / C;
  size_t cs = (size_t)H * W;
  const float* vp = v + (((size_t)n * 4 * C + 4 * c) * H + h) * W + w;
  float v0 = vp[0];
  float v1 = 2.f * vp[cs] - 1.f;
  float v2 = 2.f * vp[2 * cs] - 1.f;
  float v3 = 2.f * vp[3 * cs] - 1.f;
  int Wo = 2 * W;
  float* op = out + (((size_t)n * Ctot + c_off + c) * (2 * H) + 2 * h) * (size_t)Wo + 2 * w;
  op[0]      = v0 + 0.5f * ( v1 + v2 + v3);
  op[1]      = v0 + 0.5f * ( v1 - v2 - v3);
  op[Wo]     = v0 + 0.5f * (-v1 + v2 - v3);
  op[Wo + 1] = v0 + 0.5f * (-v1 - v2 + v3);
}

// ---------------- concat first-part copy ----------------
// src (N,C,HW) -> dst (N,Ctot,HW) channels [0,C)
__global__ void copycat_kernel(const float* __restrict__ src, float* __restrict__ dst,
                               int C, int HW, int Ctot, int total) {
  int idx = blockIdx.x * 256 + threadIdx.x;
  if (idx >= total) return;
  int p = idx % HW; int t = idx / HW;
  int c = t % C; int n = t / C;
  dst[((size_t)n * Ctot + c) * HW + p] = src[idx];
}

// ---------------- elementwise a = lrelu(a + b) ----------------
__global__ void addlrelu_kernel(float* __restrict__ a, const float* __restrict__ b, int total) {
  int idx = blockIdx.x * 256 + threadIdx.x;
  if (idx >= total) return;
  float v = a[idx] + b[idx];
  a[idx] = v > 0.f ? v : 0.2f * v;
}

// ---------------- direct 3x3 conv, pad 1, fused bias + optional lrelu ----------------
// block: 256 threads = 16x16 spatial tile; CO=4 output channels per block;
// input staged in LDS in chunks of CIC=4 channels with 1-px halo.
template <int CO, int CIC>
__global__ __launch_bounds__(256) void conv3x3_kernel(
    const float* __restrict__ in, const float* __restrict__ wgt,
    const float* __restrict__ bias, float* __restrict__ out,
    int Cin, int H, int W, int Cout, int do_lrelu) {
  __shared__ float sm[CIC][18][18];
  int tiles_x = W >> 4;
  int bt = blockIdx.x;
  int tx0 = (bt % tiles_x) << 4;
  int ty0 = (bt / tiles_x) << 4;
  int co0 = blockIdx.y * CO;
  int n = blockIdx.z;
  int tid = threadIdx.x;
  int lx = tid & 15, ly = tid >> 4;

  float acc[CO];
#pragma unroll
  for (int i = 0; i < CO; i++) acc[i] = 0.f;

  const float* inb = in + (size_t)n * Cin * H * W;

  for (int ci0 = 0; ci0 < Cin; ci0 += CIC) {
    __syncthreads();
    // stage CIC halo tiles (18x18 each)
    for (int idx = tid; idx < CIC * 324; idx += 256) {
      int ci = idx / 324;
      int r = idx - ci * 324;
      int gy = r / 18, gx = r - gy * 18;
      int iy = ty0 + gy - 1, ix = tx0 + gx - 1;
      float v = 0.f;
      if ((unsigned)iy < (unsigned)H && (unsigned)ix < (unsigned)W)
        v = inb[((size_t)(ci0 + ci)) * H * W + (size_t)iy * W + ix];
      sm[ci][gy][gx] = v;
    }
    __syncthreads();
#pragma unroll
    for (int ci = 0; ci < CIC; ci++) {
      float x00 = sm[ci][ly][lx],     x01 = sm[ci][ly][lx + 1],     x02 = sm[ci][ly][lx + 2];
      float x10 = sm[ci][ly + 1][lx], x11 = sm[ci][ly + 1][lx + 1], x12 = sm[ci][ly + 1][lx + 2];
      float x20 = sm[ci][ly + 2][lx], x21 = sm[ci][ly + 2][lx + 1], x22 = sm[ci][ly + 2][lx + 2];
      const float* wp = wgt + ((size_t)co0 * Cin + (ci0 + ci)) * 9;
#pragma unroll
      for (int co = 0; co < CO; co++) {
        const float* wc = wp + (size_t)co * Cin * 9;  // wave-uniform address -> s_load
        float a = acc[co];
        a = fmaf(wc[0], x00, a); a = fmaf(wc[1], x01, a); a = fmaf(wc[2], x02, a);
        a = fmaf(wc[3], x10, a); a = fmaf(wc[4], x11, a); a = fmaf(wc[5], x12, a);
        a = fmaf(wc[6], x20, a); a = fmaf(wc[7], x21, a); a = fmaf(wc[8], x22, a);
        acc[co] = a;
      }
    }
  }

  int oy = ty0 + ly, ox = tx0 + lx;
#pragma unroll
  for (int co = 0; co < CO; co++) {
    float v = acc[co] + bias[co0 + co];
    if (do_lrelu) v = v > 0.f ? v : 0.2f * v;
    out[(((size_t)n * Cout + co0 + co) * H + oy) * W + ox] = v;
  }
}

// ---------------- group norm, in place; one block per (group, n) ----------------
__global__ void gn_kernel(float* __restrict__ x, const float* __restrict__ gamma,
                          const float* __restrict__ beta, int C, int HW, int G) {
  __shared__ float red[512];
  int gr = blockIdx.x, n = blockIdx.y;
  int cpg = C / G;
  size_t base = ((size_t)n * C + (size_t)gr * cpg) * HW;
  int len = cpg * HW;
  float s = 0.f, s2 = 0.f;
  for (int i = threadIdx.x; i < len; i += 256) { float v = x[base + i]; s += v; s2 += v * v; }
  red[threadIdx.x] = s; red[256 + threadIdx.x] = s2;
  __syncthreads();
  for (int st = 128; st > 0; st >>= 1) {
    if (threadIdx.x < st) {
      red[threadIdx.x] += red[threadIdx.x + st];
      red[256 + threadIdx.x] += red[256 + threadIdx.x + st];
    }
    __syncthreads();
  }
  float mean = red[0] / (float)len;
  float var = red[256] / (float)len - mean * mean;  // biased (ddof=0)
  if (var < 0.f) var = 0.f;
  float inv = rsqrtf(var + 1e-5f);
  for (int i = threadIdx.x; i < len; i += 256) {
    int c = i / HW;
    float v = (x[base + i] - mean) * inv;
    x[base + i] = v * gamma[gr * cpg + c] + beta[gr * cpg + c];
  }
}

// ---------------- final 1x1 conv (3->2, ws weights, no bias) ----------------
__global__ void final_conv_kernel(const float* __restrict__ in, const float* __restrict__ w,
                                  float* __restrict__ out, int HW, int total) {
  int idx = blockIdx.x * 256 + threadIdx.x;
  if (idx >= total) return;  // total = N*HW
  int p = idx % HW; int n = idx / HW;
  const float* ip = in + (size_t)n * 3 * HW + p;
  float a = ip[0], b = ip[HW], c = ip[2 * (size_t)HW];
  float* op = out + (size_t)n * 2 * HW + p;
  op[0]  = w[0] * a + w[1] * b + w[2] * c;
  op[HW] = w[3] * a + w[4] * b + w[5] * c;
}

// ---------------------------------------------------------------------------

extern "C" void kernel_launch(void* const* d_in, const int* in_sizes, int n_in,
                              void* d_out, int out_size, void* d_ws, size_t ws_size,
                              hipStream_t stream) {
  const float* x        = (const float*)d_in[0];
  const float* conv1_w  = (const float*)d_in[1];
  const float* conv1_b  = (const float*)d_in[2];
  const float* conv2_w  = (const float*)d_in[3];
  const float* conv2_b  = (const float*)d_in[4];
  const float* conv3_w  = (const float*)d_in[5];
  const float* conv3_b  = (const float*)d_in[6];
  const float* conv4_w  = (const float*)d_in[7];
  const float* conv4_b  = (const float*)d_in[8];
  const float* convd1_w = (const float*)d_in[9];
  const float* convd1_b = (const float*)d_in[10];
  const float* convd2_w = (const float*)d_in[11];
  const float* convd2_b = (const float*)d_in[12];
  const float* convd3_w = (const float*)d_in[13];
  const float* convd3_b = (const float*)d_in[14];
  const float* convd4_w = (const float*)d_in[15];
  const float* convd4_b = (const float*)d_in[16];
  const float* final_w  = (const float*)d_in[17];
  const float* gn1_w = (const float*)d_in[18];
  const float* gn1_b = (const float*)d_in[19];
  const float* gn2_w = (const float*)d_in[20];
  const float* gn2_b = (const float*)d_in[21];
  const float* gn3_w = (const float*)d_in[22];
  const float* gn3_b = (const float*)d_in[23];
  const float* gn4_w = (const float*)d_in[24];
  const float* gn4_b = (const float*)d_in[25];

  float* ws = (float*)d_ws;
  size_t off = 0;
  auto alloc = [&](size_t nfloats) { size_t o = off; off += (nfloats + 255) & ~(size_t)255; return o; };

  // standardized weights
  size_t o_sw1  = alloc(16 * 108);
  size_t o_sw2  = alloc(64 * 576);
  size_t o_sw3  = alloc(256 * 2304);
  size_t o_sw4  = alloc(1024 * 9216);
  size_t o_swd1 = alloc(12 * 144);
  size_t o_swd2 = alloc(16 * 288);
  size_t o_swd3 = alloc(64 * 1152);
  size_t o_swd4 = alloc(256 * 4608);
  size_t o_swf  = alloc(6);
  // activations (with reuse)
  size_t o_c1 = alloc((size_t)NB * 16 * 128 * 128);    // 4.19M
  size_t o_c2 = alloc((size_t)NB * 64 * 64 * 64);      // 4.19M
  size_t o_c3 = alloc((size_t)NB * 256 * 32 * 32);     // 4.19M
  size_t o_w4 = alloc((size_t)NB * 1024 * 16 * 16);    // 4.19M
  size_t o_t1 = alloc((size_t)NB * 1024 * 16 * 16);    // 4.19M scratch
  size_t o_t2 = alloc((size_t)NB * 512 * 32 * 32);     // 8.39M scratch

  if (off * sizeof(float) > ws_size) return;  // workspace too small -> loud failure

  float* c1 = ws + o_c1;  float* c2 = ws + o_c2;  float* c3 = ws + o_c3;
  float* w4 = ws + o_w4;  float* t1 = ws + o_t1;  float* t2 = ws + o_t2;

  // ---- weight standardization ----
  ws_kernel<<<16,   256, 0, stream>>>(conv1_w,  ws + o_sw1,  108);
  ws_kernel<<<64,   256, 0, stream>>>(conv2_w,  ws + o_sw2,  576);
  ws_kernel<<<256,  256, 0, stream>>>(conv3_w,  ws + o_sw3,  2304);
  ws_kernel<<<1024, 256, 0, stream>>>(conv4_w,  ws + o_sw4,  9216);
  ws_kernel<<<12,   256, 0, stream>>>(convd1_w, ws + o_swd1, 144);
  ws_kernel<<<16,   256, 0, stream>>>(convd2_w, ws + o_swd2, 288);
  ws_kernel<<<64,   256, 0, stream>>>(convd3_w, ws + o_swd3, 1152);
  ws_kernel<<<256,  256, 0, stream>>>(convd4_w, ws + o_swd4, 4608);
  ws_kernel<<<2,    256, 0, stream>>>(final_w,  ws + o_swf,  3);

  auto launch_wt = [&](const float* in, float* out, int C, int Ho, int Wo) {
    int total = NB * C * Ho * Wo;
    wt_kernel<<<(total + 255) / 256, 256, 0, stream>>>(in, out, C, Ho, Wo, total);
  };
  auto launch_conv = [&](const float* in, const float* w, const float* b, float* out,
                         int Cin, int H, int W, int Cout, int lrelu) {
    dim3 g((W / 16) * (H / 16), Cout / 4, NB);
    conv3x3_kernel<4, 4><<<g, 256, 0, stream>>>(in, w, b, out, Cin, H, W, Cout, lrelu);
  };
  auto launch_gn = [&](float* xb, const float* g, const float* b, int C, int HW, int G) {
    dim3 gr(G, NB);
    gn_kernel<<<gr, 256, 0, stream>>>(xb, g, b, C, HW, G);
  };
  auto launch_iwt = [&](const float* v, float* out, int C, int H, int W, int c_off, int Ctot) {
    int total = NB * C * H * W;
    iwt_kernel<<<(total + 255) / 256, 256, 0, stream>>>(v, out, C, H, W, c_off, Ctot, total);
  };
  auto launch_copycat = [&](const float* src, float* dst, int C, int HW, int Ctot) {
    int total = NB * C * HW;
    copycat_kernel<<<(total + 255) / 256, 256, 0, stream>>>(src, dst, C, HW, Ctot, total);
  };

  // ---- encoder ----
  launch_wt(x, t1, 3, 128, 128);                                   // w1 -> t1 (16,12,128,128)
  launch_conv(t1, ws + o_sw1, conv1_b, c1, 12, 128, 128, 16, 1);   // c1
  launch_gn(c1, gn1_w, gn1_b, 16, 128 * 128, 2);

  launch_wt(c1, t1, 16, 64, 64);                                   // w2 -> t1 (16,64,64,64)
  launch_conv(t1, ws + o_sw2, conv2_b, c2, 64, 64, 64, 64, 1);     // c2
  launch_gn(c2, gn2_w, gn2_b, 64, 64 * 64, 8);

  launch_wt(c2, t1, 64, 32, 32);                                   // w3 -> t1 (16,256,32,32)
  launch_conv(t1, ws + o_sw3, conv3_b, c3, 256, 32, 32, 256, 1);   // c3
  launch_gn(c3, gn3_w, gn3_b, 256, 32 * 32, 32);

  launch_wt(c3, w4, 256, 16, 16);                                  // w4 (16,1024,16,16)

  launch_conv(w4, ws + o_sw4, conv4_b, t1, 1024, 16, 16, 1024, 1); // c4 -> t1
  launch_gn(t1, gn4_w, gn4_b, 1024, 16 * 16, 128);
  launch_conv(t1, ws + o_sw4, conv4_b, t2, 1024, 16, 16, 1024, 1); // c5 -> t2
  launch_gn(t2, gn4_w, gn4_b, 1024, 16 * 16, 128);
  launch_conv(t2, ws + o_sw4, conv4_b, t1, 1024, 16, 16, 1024, 0); // c6 -> t1 (no lrelu)

  {  // ic4 = lrelu(c6 + w4), in place in t1
    int total = NB * 1024 * 16 * 16;
    addlrelu_kernel<<<(total + 255) / 256, 256, 0, stream>>>(t1, w4, total);
  }

  // ---- decoder ----
  // iw4 = [c3, iwt(ic4)] -> t2 (16,512,32,32)
  launch_copycat(c3, t2, 256, 32 * 32, 512);
  launch_iwt(t1, t2, 256, 16, 16, 256, 512);
  launch_conv(t2, ws + o_swd4, convd4_b, t1, 512, 32, 32, 256, 1); // ic3 -> t1
  launch_gn(t1, gn3_w, gn3_b, 256, 32 * 32, 32);

  // iw3 = [c2, iwt(ic3)] -> t2 (16,128,64,64)
  launch_copycat(c2, t2, 64, 64 * 64, 128);
  launch_iwt(t1, t2, 64, 32, 32, 64, 128);
  launch_conv(t2, ws + o_swd3, convd3_b, t1, 128, 64, 64, 64, 1);  // ic2 -> t1
  launch_gn(t1, gn2_w, gn2_b, 64, 64 * 64, 8);

  // iw2 = [c1, iwt(ic2)] -> t2 (16,32,128,128)
  launch_copycat(c1, t2, 16, 128 * 128, 32);
  launch_iwt(t1, t2, 16, 64, 64, 16, 32);
  launch_conv(t2, ws + o_swd2, convd2_b, t1, 32, 128, 128, 16, 1); // ic1 -> t1
  launch_gn(t1, gn1_w, gn1_b, 16, 128 * 128, 2);

  launch_conv(t1, ws + o_swd1, convd1_b, t2, 16, 128, 128, 12, 1); // iw1 -> t2 (lrelu, no gn)

  launch_iwt(t2, t1, 3, 128, 128, 0, 3);                           // iwt(iw1) -> t1 (16,3,256,256)

  {  // y = ws_conv(t1, final_w, None, 0) -> d_out (16,2,256,256)
    int total = NB * 256 * 256;
    final_conv_kernel<<<(total + 255) / 256, 256, 0, stream>>>(t1, ws + o_swf, (float*)d_out,
                                                               256 * 256, total);
  }
}

// Round 2
// 1907.330 us; speedup vs baseline: 5.7333x; 5.7333x over previous
//
#include <hip/hip_runtime.h>
#include <math.h>

// ---------------------------------------------------------------------------
// WaveletNet forward. Big convs via f16 MFMA implicit GEMM (tap-wise),
// small convs direct fp32. N=16 fixed, NCHW fp32 activations + NHWC f16
// mirrors for MFMA inputs.
// ---------------------------------------------------------------------------

#define NB 16  // batch

typedef _Float16 f16;
typedef _Float16 f16x8 __attribute__((ext_vector_type(8)));
typedef float f32x4 __attribute__((ext_vector_type(4)));

// ---------------- weight standardization (fp32 out, for direct convs) -------
__global__ void ws_kernel(const float* __restrict__ w, float* __restrict__ out, int fan) {
  __shared__ float red[512];
  int o = blockIdx.x;
  const float* wp = w + (size_t)o * fan;
  float s = 0.f, s2 = 0.f;
  for (int i = threadIdx.x; i < fan; i += 256) { float v = wp[i]; s += v; s2 += v * v; }
  red[threadIdx.x] = s; red[256 + threadIdx.x] = s2;
  __syncthreads();
  for (int st = 128; st > 0; st >>= 1) {
    if (threadIdx.x < st) {
      red[threadIdx.x] += red[threadIdx.x + st];
      red[256 + threadIdx.x] += red[256 + threadIdx.x + st];
    }
    __syncthreads();
  }
  float sum = red[0], sumsq = red[256];
  float mean = sum / (float)fan;
  float var = (sumsq - sum * mean) / (float)(fan - 1);
  if (var < 0.f) var = 0.f;
  float inv = 1.0f / (sqrtf(var) + 1e-5f);
  for (int i = threadIdx.x; i < fan; i += 256)
    out[(size_t)o * fan + i] = (wp[i] - mean) * inv;
}

// ---------------- weight standardization + f16 pack [tap][Cout][Cin] --------
__global__ void ws_f16_kernel(const float* __restrict__ w, f16* __restrict__ out,
                              int fan, int Cin, int Cout) {
  __shared__ float red[512];
  int o = blockIdx.x;
  const float* wp = w + (size_t)o * fan;
  float s = 0.f, s2 = 0.f;
  for (int i = threadIdx.x; i < fan; i += 256) { float v = wp[i]; s += v; s2 += v * v; }
  red[threadIdx.x] = s; red[256 + threadIdx.x] = s2;
  __syncthreads();
  for (int st = 128; st > 0; st >>= 1) {
    if (threadIdx.x < st) {
      red[threadIdx.x] += red[threadIdx.x + st];
      red[256 + threadIdx.x] += red[256 + threadIdx.x + st];
    }
    __syncthreads();
  }
  float sum = red[0], sumsq = red[256];
  float mean = sum / (float)fan;
  float var = (sumsq - sum * mean) / (float)(fan - 1);
  if (var < 0.f) var = 0.f;
  float inv = 1.0f / (sqrtf(var) + 1e-5f);
  for (int i = threadIdx.x; i < fan; i += 256) {
    int ci = i / 9, tap = i - ci * 9;
    out[((size_t)tap * Cout + o) * Cin + ci] = (f16)((wp[i] - mean) * inv);
  }
}

// ---------------- NCHW fp32 -> NHWC f16 transpose ----------------
// grid: (HW/256, C/32, N)
__global__ __launch_bounds__(256) void to_nhwc_kernel(const float* __restrict__ in,
                                                      f16* __restrict__ out, int C, int HW) {
  __shared__ f16 sm[32][264];
  int p0 = blockIdx.x * 256, c0 = blockIdx.y * 32, n = blockIdx.z;
  int t = threadIdx.x;
  const float* ip = in + ((size_t)n * C + c0) * HW + p0;
#pragma unroll 8
  for (int r = 0; r < 32; ++r) sm[r][t] = (f16)ip[(size_t)r * HW + t];
  __syncthreads();
#pragma unroll
  for (int i = 0; i < 4; ++i) {
    int c = t + i * 256;
    int pl = c >> 2, cio = (c & 3) * 8;
    f16x8 v;
#pragma unroll
    for (int u = 0; u < 8; ++u) v[u] = sm[cio + u][pl];
    *(f16x8*)(out + ((size_t)(n * HW + p0 + pl)) * C + c0 + cio) = v;
  }
}

// ---------------- MFMA implicit-GEMM 3x3 conv ----------------
// A: NHWC f16 activations (rows m = n*HW+p, cols ci). Wp: [9][Cout][Cin] f16.
// out: NCHW fp32, fused bias + optional lrelu. Tap-wise K accumulation.
// Block: 256 thr = 4 waves (2x2), tile BM=128 x BN=64, BK=32, 16x16x32 MFMA.
template <int WN>
__global__ __launch_bounds__(256) void conv_mfma_kernel(
    const f16* __restrict__ A, const f16* __restrict__ Wp,
    const float* __restrict__ bias, float* __restrict__ out,
    int Cin, int H, int W, int Cout, int HW, int do_lrelu) {
  constexpr int BM = 128, BN = 32 * WN, LDK = 48;
  __shared__ f16 Asm[BM * LDK];
  __shared__ f16 Bsm[BN * LDK];

  const int tid = threadIdx.x;
  const int m0 = blockIdx.x * BM;
  const int co0 = blockIdx.y * BN;

  // A staging: 512 x 16B chunks, 2/thread. Precompute row geometry.
  int ax[2], ay[2];
  long abase[2];
  int arow[2], aq[2];
#pragma unroll
  for (int i = 0; i < 2; ++i) {
    int c = tid + i * 256;
    arow[i] = c >> 2; aq[i] = c & 3;
    int m = m0 + arow[i];
    int p = m % HW;
    ay[i] = p / W; ax[i] = p % W;
    abase[i] = (long)m * Cin + aq[i] * 8;
  }
  // B staging: BN*4 chunks (<=256), 1/thread
  const int brow = (tid >> 2) % BN, bq = tid & 3;
  const long bbase = (long)(co0 + brow) * Cin + bq * 8;
  const bool bact = (tid < BN * 4);

  const int lane = tid & 63, wid = tid >> 6;
  const int wm = wid & 1, wn = wid >> 1;
  const int lr = lane & 15, quad = lane >> 4;
  const int aoff = (wm * 64 + lr) * LDK + quad * 8;
  const int boff = (wn * (BN / 2) + lr) * LDK + quad * 8;

  f32x4 acc[4][WN];
#pragma unroll
  for (int i = 0; i < 4; ++i)
#pragma unroll
    for (int j = 0; j < WN; ++j) acc[i][j] = (f32x4){0.f, 0.f, 0.f, 0.f};

  for (int tap = 0; tap < 9; ++tap) {
    const int dy = tap / 3 - 1, dx = tap % 3 - 1;
    const long shift = ((long)dy * W + dx) * Cin;
    bool av[2];
#pragma unroll
    for (int i = 0; i < 2; ++i)
      av[i] = ((unsigned)(ay[i] + dy) < (unsigned)H) && ((unsigned)(ax[i] + dx) < (unsigned)W);
    const f16* wt_tap = Wp + (size_t)tap * Cout * Cin;

    for (int kc = 0; kc < Cin; kc += 32) {
      __syncthreads();
#pragma unroll
      for (int i = 0; i < 2; ++i) {
        uint4 v = make_uint4(0u, 0u, 0u, 0u);
        if (av[i]) v = *(const uint4*)(A + abase[i] + shift + kc);
        *(uint4*)&Asm[arow[i] * LDK + aq[i] * 8] = v;
      }
      if (bact)
        *(uint4*)&Bsm[brow * LDK + bq * 8] = *(const uint4*)(wt_tap + bbase + kc);
      __syncthreads();

      f16x8 af[4], bf[WN];
#pragma unroll
      for (int i = 0; i < 4; ++i) af[i] = *(const f16x8*)&Asm[aoff + i * 16 * LDK];
#pragma unroll
      for (int j = 0; j < WN; ++j) bf[j] = *(const f16x8*)&Bsm[boff + j * 16 * LDK];
#pragma unroll
      for (int i = 0; i < 4; ++i)
#pragma unroll
        for (int j = 0; j < WN; ++j)
          acc[i][j] = __builtin_amdgcn_mfma_f32_16x16x32_f16(af[i], bf[j], acc[i][j], 0, 0, 0);
    }
  }

  // epilogue: D col = co (lane&15), rows = m (quad*4 + reg)
#pragma unroll
  for (int i = 0; i < 4; ++i) {
    int mg = m0 + wm * 64 + i * 16 + quad * 4;
    int n = mg / HW, p = mg % HW;
#pragma unroll
    for (int j = 0; j < WN; ++j) {
      int co = co0 + wn * (BN / 2) + j * 16 + lr;
      float b = bias[co];
      f32x4 v = acc[i][j];
#pragma unroll
      for (int r = 0; r < 4; ++r) {
        float u = v[r] + b;
        v[r] = (do_lrelu && u < 0.f) ? 0.2f * u : u;
      }
      *(f32x4*)&out[((size_t)n * Cout + co) * HW + p] = v;
    }
  }
}

// ---------------- Haar forward (wt) ----------------
__global__ void wt_kernel(const float* __restrict__ in, float* __restrict__ out,
                          int C, int Ho, int Wo, int total) {
  int idx = blockIdx.x * 256 + threadIdx.x;
  if (idx >= total) return;
  int w = idx % Wo; int t = idx / Wo;
  int h = t % Ho; t /= Ho;
  int c = t % C; int n = t / C;
  int Wi = 2 * Wo;
  const float* ip = in + (((size_t)n * C + c) * (2 * Ho) + 2 * h) * Wi + 2 * w;
  float a = ip[0], b = ip[1], cc = ip[Wi], d = ip[Wi + 1];
  size_t cs = (size_t)Ho * Wo;
  float* op = out + (((size_t)n * 4 * C + 4 * c) * Ho + h) * Wo + w;
  op[0]      = 0.25f * (a + b + cc + d);
  op[cs]     = 0.25f * (a + b - cc - d) + 0.5f;
  op[2 * cs] = 0.25f * (a - b + cc - d) + 0.5f;
  op[3 * cs] = 0.25f * (a - b - cc + d) + 0.5f;
}

// ---------------- Haar inverse (iwt) ----------------
__global__ void iwt_kernel(const float* __restrict__ v, float* __restrict__ out,
                           int C, int H, int W, int c_off, int Ctot, int total) {
  int idx = blockIdx.x * 256 + threadIdx.x;
  if (idx >= total) return;
  int w = idx % W; int t = idx / W;
  int h = t % H; t /= H;
  int c = t % C; int n = t / C;
  size_t cs = (size_t)H * W;
  const float* vp = v + (((size_t)n * 4 * C + 4 * c) * H + h) * W + w;
  float v0 = vp[0];
  float v1 = 2.f * vp[cs] - 1.f;
  float v2 = 2.f * vp[2 * cs] - 1.f;
  float v3 = 2.f * vp[3 * cs] - 1.f;
  int Wo = 2 * W;
  float* op = out + (((size_t)n * Ctot + c_off + c) * (2 * H) + 2 * h) * (size_t)Wo + 2 * w;
  op[0]      = v0 + 0.5f * ( v1 + v2 + v3);
  op[1]      = v0 + 0.5f * ( v1 - v2 - v3);
  op[Wo]     = v0 + 0.5f * (-v1 + v2 - v3);
  op[Wo + 1] = v0 + 0.5f * (-v1 - v2 + v3);
}

// ---------------- concat first-part copy ----------------
__global__ void copycat_kernel(const float* __restrict__ src, float* __restrict__ dst,
                               int C, int HW, int Ctot, int total) {
  int idx = blockIdx.x * 256 + threadIdx.x;
  if (idx >= total) return;
  int p = idx % HW; int t = idx / HW;
  int c = t % C; int n = t / C;
  dst[((size_t)n * Ctot + c) * HW + p] = src[idx];
}

// ---------------- a = lrelu(a + b) ----------------
__global__ void addlrelu_kernel(float* __restrict__ a, const float* __restrict__ b, int total) {
  int idx = blockIdx.x * 256 + threadIdx.x;
  if (idx >= total) return;
  float v = a[idx] + b[idx];
  a[idx] = v > 0.f ? v : 0.2f * v;
}

// ---------------- direct 3x3 conv (small channel counts) ----------------
template <int CO, int CIC>
__global__ __launch_bounds__(256) void conv3x3_kernel(
    const float* __restrict__ in, const float* __restrict__ wgt,
    const float* __restrict__ bias, float* __restrict__ out,
    int Cin, int H, int W, int Cout, int do_lrelu) {
  __shared__ float sm[CIC][18][18];
  int tiles_x = W >> 4;
  int bt = blockIdx.x;
  int tx0 = (bt % tiles_x) << 4;
  int ty0 = (bt / tiles_x) << 4;
  int co0 = blockIdx.y * CO;
  int n = blockIdx.z;
  int tid = threadIdx.x;
  int lx = tid & 15, ly = tid >> 4;

  float acc[CO];
#pragma unroll
  for (int i = 0; i < CO; i++) acc[i] = 0.f;

  const float* inb = in + (size_t)n * Cin * H * W;

  for (int ci0 = 0; ci0 < Cin; ci0 += CIC) {
    __syncthreads();
    for (int idx = tid; idx < CIC * 324; idx += 256) {
      int ci = idx / 324;
      int r = idx - ci * 324;
      int gy = r / 18, gx = r - gy * 18;
      int iy = ty0 + gy - 1, ix = tx0 + gx - 1;
      float v = 0.f;
      if ((unsigned)iy < (unsigned)H && (unsigned)ix < (unsigned)W)
        v = inb[((size_t)(ci0 + ci)) * H * W + (size_t)iy * W + ix];
      sm[ci][gy][gx] = v;
    }
    __syncthreads();
#pragma unroll
    for (int ci = 0; ci < CIC; ci++) {
      float x00 = sm[ci][ly][lx],     x01 = sm[ci][ly][lx + 1],     x02 = sm[ci][ly][lx + 2];
      float x10 = sm[ci][ly + 1][lx], x11 = sm[ci][ly + 1][lx + 1], x12 = sm[ci][ly + 1][lx + 2];
      float x20 = sm[ci][ly + 2][lx], x21 = sm[ci][ly + 2][lx + 1], x22 = sm[ci][ly + 2][lx + 2];
      const float* wp = wgt + ((size_t)co0 * Cin + (ci0 + ci)) * 9;
#pragma unroll
      for (int co = 0; co < CO; co++) {
        const float* wc = wp + (size_t)co * Cin * 9;
        float a = acc[co];
        a = fmaf(wc[0], x00, a); a = fmaf(wc[1], x01, a); a = fmaf(wc[2], x02, a);
        a = fmaf(wc[3], x10, a); a = fmaf(wc[4], x11, a); a = fmaf(wc[5], x12, a);
        a = fmaf(wc[6], x20, a); a = fmaf(wc[7], x21, a); a = fmaf(wc[8], x22, a);
        acc[co] = a;
      }
    }
  }

  int oy = ty0 + ly, ox = tx0 + lx;
#pragma unroll
  for (int co = 0; co < CO; co++) {
    float v = acc[co] + bias[co0 + co];
    if (do_lrelu) v = v > 0.f ? v : 0.2f * v;
    out[(((size_t)n * Cout + co0 + co) * H + oy) * W + ox] = v;
  }
}

// ---------------- group norm (in place) ----------------
__global__ void gn_kernel(float* __restrict__ x, const float* __restrict__ gamma,
                          const float* __restrict__ beta, int C, int HW, int G) {
  __shared__ float red[512];
  int gr = blockIdx.x, n = blockIdx.y;
  int cpg = C / G;
  size_t base = ((size_t)n * C + (size_t)gr * cpg) * HW;
  int len = cpg * HW;
  float s = 0.f, s2 = 0.f;
  for (int i = threadIdx.x; i < len; i += 256) { float v = x[base + i]; s += v; s2 += v * v; }
  red[threadIdx.x] = s; red[256 + threadIdx.x] = s2;
  __syncthreads();
  for (int st = 128; st > 0; st >>= 1) {
    if (threadIdx.x < st) {
      red[threadIdx.x] += red[threadIdx.x + st];
      red[256 + threadIdx.x] += red[256 + threadIdx.x + st];
    }
    __syncthreads();
  }
  float mean = red[0] / (float)len;
  float var = red[256] / (float)len - mean * mean;
  if (var < 0.f) var = 0.f;
  float inv = rsqrtf(var + 1e-5f);
  for (int i = threadIdx.x; i < len; i += 256) {
    int c = i / HW;
    float v = (x[base + i] - mean) * inv;
    x[base + i] = v * gamma[gr * cpg + c] + beta[gr * cpg + c];
  }
}

// ---------------- final 1x1 conv ----------------
__global__ void final_conv_kernel(const float* __restrict__ in, const float* __restrict__ w,
                                  float* __restrict__ out, int HW, int total) {
  int idx = blockIdx.x * 256 + threadIdx.x;
  if (idx >= total) return;
  int p = idx % HW; int n = idx / HW;
  const float* ip = in + (size_t)n * 3 * HW + p;
  float a = ip[0], b = ip[HW], c = ip[2 * (size_t)HW];
  float* op = out + (size_t)n * 2 * HW + p;
  op[0]  = w[0] * a + w[1] * b + w[2] * c;
  op[HW] = w[3] * a + w[4] * b + w[5] * c;
}

// ---------------------------------------------------------------------------

extern "C" void kernel_launch(void* const* d_in, const int* in_sizes, int n_in,
                              void* d_out, int out_size, void* d_ws, size_t ws_size,
                              hipStream_t stream) {
  const float* x        = (const float*)d_in[0];
  const float* conv1_w  = (const float*)d_in[1];
  const float* conv1_b  = (const float*)d_in[2];
  const float* conv2_w  = (const float*)d_in[3];
  const float* conv2_b  = (const float*)d_in[4];
  const float* conv3_w  = (const float*)d_in[5];
  const float* conv3_b  = (const float*)d_in[6];
  const float* conv4_w  = (const float*)d_in[7];
  const float* conv4_b  = (const float*)d_in[8];
  const float* convd1_w = (const float*)d_in[9];
  const float* convd1_b = (const float*)d_in[10];
  const float* convd2_w = (const float*)d_in[11];
  const float* convd2_b = (const float*)d_in[12];
  const float* convd3_w = (const float*)d_in[13];
  const float* convd3_b = (const float*)d_in[14];
  const float* convd4_w = (const float*)d_in[15];
  const float* convd4_b = (const float*)d_in[16];
  const float* final_w  = (const float*)d_in[17];
  const float* gn1_w = (const float*)d_in[18];
  const float* gn1_b = (const float*)d_in[19];
  const float* gn2_w = (const float*)d_in[20];
  const float* gn2_b = (const float*)d_in[21];
  const float* gn3_w = (const float*)d_in[22];
  const float* gn3_b = (const float*)d_in[23];
  const float* gn4_w = (const float*)d_in[24];
  const float* gn4_b = (const float*)d_in[25];

  char* base = (char*)d_ws;
  size_t off = 0;
  auto allocB = [&](size_t bytes) { size_t o = off; off = (off + bytes + 255) & ~(size_t)255; return o; };

  // fp32 standardized weights (direct convs)
  size_t o_sw1  = allocB(16 * 108 * 4);
  size_t o_swd1 = allocB(12 * 144 * 4);
  size_t o_swd2 = allocB(16 * 288 * 4);
  size_t o_swf  = allocB(6 * 4);
  // f16 packed weights [tap][Cout][Cin]
  size_t o_pw2  = allocB((size_t)9 * 64 * 64 * 2);
  size_t o_pw3  = allocB((size_t)9 * 256 * 256 * 2);
  size_t o_pw4  = allocB((size_t)9 * 1024 * 1024 * 2);
  size_t o_pwd3 = allocB((size_t)9 * 64 * 128 * 2);
  size_t o_pwd4 = allocB((size_t)9 * 256 * 512 * 2);
  // f16 NHWC activation mirror (max 16*512*1024 = 8.39M elems)
  size_t o_ah   = allocB((size_t)16 * 512 * 1024 * 2);
  // fp32 activations
  size_t o_c1 = allocB((size_t)NB * 16 * 128 * 128 * 4);
  size_t o_c2 = allocB((size_t)NB * 64 * 64 * 64 * 4);
  size_t o_c3 = allocB((size_t)NB * 256 * 32 * 32 * 4);
  size_t o_w4 = allocB((size_t)NB * 1024 * 16 * 16 * 4);
  size_t o_t1 = allocB((size_t)NB * 1024 * 16 * 16 * 4);
  size_t o_t2 = allocB((size_t)NB * 512 * 32 * 32 * 4);

  if (off > ws_size) return;

  float* c1 = (float*)(base + o_c1);
  float* c2 = (float*)(base + o_c2);
  float* c3 = (float*)(base + o_c3);
  float* w4 = (float*)(base + o_w4);
  float* t1 = (float*)(base + o_t1);
  float* t2 = (float*)(base + o_t2);
  f16* ah = (f16*)(base + o_ah);
  f16* pw2 = (f16*)(base + o_pw2);
  f16* pw3 = (f16*)(base + o_pw3);
  f16* pw4 = (f16*)(base + o_pw4);
  f16* pwd3 = (f16*)(base + o_pwd3);
  f16* pwd4 = (f16*)(base + o_pwd4);

  // ---- weight prep ----
  ws_kernel<<<16, 256, 0, stream>>>(conv1_w,  (float*)(base + o_sw1),  108);
  ws_kernel<<<12, 256, 0, stream>>>(convd1_w, (float*)(base + o_swd1), 144);
  ws_kernel<<<16, 256, 0, stream>>>(convd2_w, (float*)(base + o_swd2), 288);
  ws_kernel<<<2,  256, 0, stream>>>(final_w,  (float*)(base + o_swf),  3);
  ws_f16_kernel<<<64,   256, 0, stream>>>(conv2_w,  pw2,  576,  64,   64);
  ws_f16_kernel<<<256,  256, 0, stream>>>(conv3_w,  pw3,  2304, 256,  256);
  ws_f16_kernel<<<1024, 256, 0, stream>>>(conv4_w,  pw4,  9216, 1024, 1024);
  ws_f16_kernel<<<64,   256, 0, stream>>>(convd3_w, pwd3, 1152, 128,  64);
  ws_f16_kernel<<<256,  256, 0, stream>>>(convd4_w, pwd4, 4608, 512,  256);

  auto launch_wt = [&](const float* in, float* out, int C, int Ho, int Wo) {
    int total = NB * C * Ho * Wo;
    wt_kernel<<<(total + 255) / 256, 256, 0, stream>>>(in, out, C, Ho, Wo, total);
  };
  auto launch_tr = [&](const float* in, f16* outh, int C, int HW) {
    dim3 g(HW / 256, C / 32, NB);
    to_nhwc_kernel<<<g, 256, 0, stream>>>(in, outh, C, HW);
  };
  auto launch_cmfma = [&](const f16* a, const f16* w, const float* b, float* o,
                          int Cin, int Hs, int Ws, int Cout, int lr) {
    dim3 g((NB * Hs * Ws) / 128, Cout / 64);
    conv_mfma_kernel<2><<<g, 256, 0, stream>>>(a, w, b, o, Cin, Hs, Ws, Cout, Hs * Ws, lr);
  };
  auto launch_conv = [&](const float* in, const float* w, const float* b, float* out,
                         int Cin, int H, int W, int Cout, int lrelu) {
    dim3 g((W / 16) * (H / 16), Cout / 4, NB);
    conv3x3_kernel<4, 4><<<g, 256, 0, stream>>>(in, w, b, out, Cin, H, W, Cout, lrelu);
  };
  auto launch_gn = [&](float* xb, const float* g, const float* b, int C, int HW, int G) {
    dim3 gr(G, NB);
    gn_kernel<<<gr, 256, 0, stream>>>(xb, g, b, C, HW, G);
  };
  auto launch_iwt = [&](const float* v, float* out, int C, int H, int W, int c_off, int Ctot) {
    int total = NB * C * H * W;
    iwt_kernel<<<(total + 255) / 256, 256, 0, stream>>>(v, out, C, H, W, c_off, Ctot, total);
  };
  auto launch_copycat = [&](const float* src, float* dst, int C, int HW, int Ctot) {
    int total = NB * C * HW;
    copycat_kernel<<<(total + 255) / 256, 256, 0, stream>>>(src, dst, C, HW, Ctot, total);
  };

  // ---- encoder ----
  launch_wt(x, t1, 3, 128, 128);                                   // w1 (16,12,128,128)
  launch_conv(t1, (float*)(base + o_sw1), conv1_b, c1, 12, 128, 128, 16, 1);
  launch_gn(c1, gn1_w, gn1_b, 16, 128 * 128, 2);

  launch_wt(c1, t1, 16, 64, 64);                                   // w2 (16,64,64,64)
  launch_tr(t1, ah, 64, 64 * 64);
  launch_cmfma(ah, pw2, conv2_b, c2, 64, 64, 64, 64, 1);           // c2
  launch_gn(c2, gn2_w, gn2_b, 64, 64 * 64, 8);

  launch_wt(c2, t1, 64, 32, 32);                                   // w3 (16,256,32,32)
  launch_tr(t1, ah, 256, 32 * 32);
  launch_cmfma(ah, pw3, conv3_b, c3, 256, 32, 32, 256, 1);         // c3
  launch_gn(c3, gn3_w, gn3_b, 256, 32 * 32, 32);

  launch_wt(c3, w4, 256, 16, 16);                                  // w4 (16,1024,16,16)

  launch_tr(w4, ah, 1024, 256);
  launch_cmfma(ah, pw4, conv4_b, t1, 1024, 16, 16, 1024, 1);       // c4 -> t1
  launch_gn(t1, gn4_w, gn4_b, 1024, 16 * 16, 128);
  launch_tr(t1, ah, 1024, 256);
  launch_cmfma(ah, pw4, conv4_b, t2, 1024, 16, 16, 1024, 1);       // c5 -> t2
  launch_gn(t2, gn4_w, gn4_b, 1024, 16 * 16, 128);
  launch_tr(t2, ah, 1024, 256);
  launch_cmfma(ah, pw4, conv4_b, t1, 1024, 16, 16, 1024, 0);       // c6 -> t1

  {  // ic4 = lrelu(c6 + w4) in t1
    int total = NB * 1024 * 16 * 16;
    addlrelu_kernel<<<(total + 255) / 256, 256, 0, stream>>>(t1, w4, total);
  }

  // ---- decoder ----
  launch_copycat(c3, t2, 256, 32 * 32, 512);                       // iw4 -> t2
  launch_iwt(t1, t2, 256, 16, 16, 256, 512);
  launch_tr(t2, ah, 512, 32 * 32);
  launch_cmfma(ah, pwd4, convd4_b, t1, 512, 32, 32, 256, 1);       // ic3 -> t1
  launch_gn(t1, gn3_w, gn3_b, 256, 32 * 32, 32);

  launch_copycat(c2, t2, 64, 64 * 64, 128);                        // iw3 -> t2
  launch_iwt(t1, t2, 64, 32, 32, 64, 128);
  launch_tr(t2, ah, 128, 64 * 64);
  launch_cmfma(ah, pwd3, convd3_b, t1, 128, 64, 64, 64, 1);        // ic2 -> t1
  launch_gn(t1, gn2_w, gn2_b, 64, 64 * 64, 8);

  launch_copycat(c1, t2, 16, 128 * 128, 32);                       // iw2 -> t2
  launch_iwt(t1, t2, 16, 64, 64, 16, 32);
  launch_conv(t2, (float*)(base + o_swd2), convd2_b, t1, 32, 128, 128, 16, 1);  // ic1
  launch_gn(t1, gn1_w, gn1_b, 16, 128 * 128, 2);

  launch_conv(t1, (float*)(base + o_swd1), convd1_b, t2, 16, 128, 128, 12, 1);  // iw1

  launch_iwt(t2, t1, 3, 128, 128, 0, 3);                           // iwt(iw1) (16,3,256,256)

  {  // final 1x1
    int total = NB * 256 * 256;
    final_conv_kernel<<<(total + 255) / 256, 256, 0, stream>>>(t1, (float*)(base + o_swf),
                                                               (float*)d_out, 256 * 256, total);
  }
}

// Round 3
// 1537.851 us; speedup vs baseline: 7.1107x; 1.2403x over previous
//
#include <hip/hip_runtime.h>
#include <math.h>

// ---------------------------------------------------------------------------
// WaveletNet forward. Big convs via f16 MFMA implicit GEMM (tap-wise) with
// global_load_lds async staging from a zero-halo-padded NHWC f16 mirror.
// Small convs direct fp32. N=16 fixed.
// ---------------------------------------------------------------------------

#define NB 16  // batch

typedef _Float16 f16;
typedef _Float16 f16x8 __attribute__((ext_vector_type(8)));
typedef float f32x4 __attribute__((ext_vector_type(4)));
typedef unsigned int u32;

// async global->LDS 16B: lds dest must be wave-uniform base (+lane*16 by HW)
#define LLDS16(gp, lp)                                                          \
  __builtin_amdgcn_global_load_lds((const __attribute__((address_space(1))) u32*)(const void*)(gp), \
                                   (__attribute__((address_space(3))) u32*)(void*)(lp), 16, 0, 0)

// ---------------- weight standardization (fp32 out, for direct convs) -------
__global__ void ws_kernel(const float* __restrict__ w, float* __restrict__ out, int fan) {
  __shared__ float red[512];
  int o = blockIdx.x;
  const float* wp = w + (size_t)o * fan;
  float s = 0.f, s2 = 0.f;
  for (int i = threadIdx.x; i < fan; i += 256) { float v = wp[i]; s += v; s2 += v * v; }
  red[threadIdx.x] = s; red[256 + threadIdx.x] = s2;
  __syncthreads();
  for (int st = 128; st > 0; st >>= 1) {
    if (threadIdx.x < st) {
      red[threadIdx.x] += red[threadIdx.x + st];
      red[256 + threadIdx.x] += red[256 + threadIdx.x + st];
    }
    __syncthreads();
  }
  float sum = red[0], sumsq = red[256];
  float mean = sum / (float)fan;
  float var = (sumsq - sum * mean) / (float)(fan - 1);
  if (var < 0.f) var = 0.f;
  float inv = 1.0f / (sqrtf(var) + 1e-5f);
  for (int i = threadIdx.x; i < fan; i += 256)
    out[(size_t)o * fan + i] = (wp[i] - mean) * inv;
}

// ---------------- weight standardization + f16 pack [tap][Cout][Cin] --------
__global__ void ws_f16_kernel(const float* __restrict__ w, f16* __restrict__ out,
                              int fan, int Cin, int Cout) {
  __shared__ float red[512];
  int o = blockIdx.x;
  const float* wp = w + (size_t)o * fan;
  float s = 0.f, s2 = 0.f;
  for (int i = threadIdx.x; i < fan; i += 256) { float v = wp[i]; s += v; s2 += v * v; }
  red[threadIdx.x] = s; red[256 + threadIdx.x] = s2;
  __syncthreads();
  for (int st = 128; st > 0; st >>= 1) {
    if (threadIdx.x < st) {
      red[threadIdx.x] += red[threadIdx.x + st];
      red[256 + threadIdx.x] += red[256 + threadIdx.x + st];
    }
    __syncthreads();
  }
  float sum = red[0], sumsq = red[256];
  float mean = sum / (float)fan;
  float var = (sumsq - sum * mean) / (float)(fan - 1);
  if (var < 0.f) var = 0.f;
  float inv = 1.0f / (sqrtf(var) + 1e-5f);
  for (int i = threadIdx.x; i < fan; i += 256) {
    int ci = i / 9, tap = i - ci * 9;
    out[((size_t)tap * Cout + o) * Cin + ci] = (f16)((wp[i] - mean) * inv);
  }
}

// ---------------- zero the 1-px halo of a padded NHWC f16 buffer ------------
__global__ void zero_halo_kernel(f16* __restrict__ buf, int C, int H, int W, int total8) {
  int idx = blockIdx.x * 256 + threadIdx.x;
  if (idx >= total8) return;
  int c8s = C >> 3;
  int c8 = idx % c8s; int t = idx / c8s;
  int P = 2 * (W + 2) + 2 * H;
  int b = t % P; int n = t / P;
  int y, x;
  if (b < W + 2) { y = 0; x = b; }
  else if (b < 2 * (W + 2)) { y = H + 1; x = b - (W + 2); }
  else { int bb = b - 2 * (W + 2); y = 1 + (bb >> 1); x = (bb & 1) ? (W + 1) : 0; }
  size_t a = (((size_t)n * (H + 2) + y) * (W + 2) + x) * C + c8 * 8;
  f16x8 z = {0, 0, 0, 0, 0, 0, 0, 0};
  *(f16x8*)(buf + a) = z;
}

// ---------------- NCHW fp32 -> padded NHWC f16 transpose ----------------
// grid: (HW/256, C/32, N); interior written, halo untouched (zeroed separately)
__global__ __launch_bounds__(256) void to_nhwc_pad_kernel(const float* __restrict__ in,
                                                          f16* __restrict__ out,
                                                          int C, int H, int W) {
  __shared__ f16 sm[32][264];
  int HW = H * W;
  int p0 = blockIdx.x * 256, c0 = blockIdx.y * 32, n = blockIdx.z;
  int t = threadIdx.x;
  const float* ip = in + ((size_t)n * C + c0) * HW + p0;
#pragma unroll 8
  for (int r = 0; r < 32; ++r) sm[r][t] = (f16)ip[(size_t)r * HW + t];
  __syncthreads();
#pragma unroll
  for (int i = 0; i < 4; ++i) {
    int c = t + i * 256;
    int pl = c >> 2, cio = (c & 3) * 8;
    f16x8 v;
#pragma unroll
    for (int u = 0; u < 8; ++u) v[u] = sm[cio + u][pl];
    int p = p0 + pl; int y = p / W; int x = p - y * W;
    *(f16x8*)(out + (((size_t)n * (H + 2) + y + 1) * (W + 2) + x + 1) * C + c0 + cio) = v;
  }
}

// ---------------- MFMA implicit-GEMM 3x3 conv, v2 ----------------
// A: padded NHWC f16 (halo zeroed). Wp: [9][Cout][Cin] f16. out: NCHW fp32.
// Block: 256 thr = 4 waves (2x2), tile BM=128 x BN=64, BK=64, 16x16x32 MFMA.
// Staging via global_load_lds w=16; XOR swizzle (chunk ^ (row&7)) applied on
// the global address so ds_read_b128 fragment reads are conflict-free.
__global__ __launch_bounds__(256) void conv_mfma2_kernel(
    const f16* __restrict__ A, const f16* __restrict__ Wp,
    const float* __restrict__ bias, float* __restrict__ out,
    int Cin, int H, int W, int Cout, int HW, int do_lrelu) {
  constexpr int BM = 128, BN = 64, BK = 64;
  __shared__ f16 Asm[BM * BK];  // 16 KB
  __shared__ f16 Bsm[BN * BK];  // 8 KB

  const int tid = threadIdx.x;
  const int w = tid >> 6, lane = tid & 63;
  const int m0 = blockIdx.x * BM;
  const int co0 = blockIdx.y * BN;
  const int Wp2 = W + 2;

  // ---- A staging geometry: 1024 chunks of 16B, 4 issues/thread ----
  const f16* gA[4];
  int lAoff[4];
#pragma unroll
  for (int e = 0; e < 4; ++e) {
    int c = e * 256 + tid;
    int r = c >> 3, j = c & 7;
    int jx = j ^ (r & 7);
    int m = m0 + r; int n = m / HW; int p = m - n * HW;
    int y = p / W; int x = p - y * W;
    gA[e] = A + (((size_t)n * (H + 2) + y + 1) * Wp2 + (x + 1)) * Cin + jx * 8;
    lAoff[e] = (e * 256 + w * 64) * 8;  // wave-uniform
  }
  // ---- B staging: 512 chunks, 2 issues/thread ----
  const f16* gB[2];
  int lBoff[2];
#pragma unroll
  for (int e = 0; e < 2; ++e) {
    int c = e * 256 + tid;
    int r = c >> 3, j = c & 7;
    int jx = j ^ (r & 7);
    gB[e] = Wp + (size_t)(co0 + r) * Cin + jx * 8;
    lBoff[e] = (e * 256 + w * 64) * 8;
  }

  // ---- fragment read offsets (swizzled) ----
  const int wm = w & 1, wn = w >> 1;
  const int lr = lane & 15, quad = lane >> 4;
  int aoffs[4][2], boffs[2][2];
#pragma unroll
  for (int i = 0; i < 4; ++i)
#pragma unroll
    for (int kk = 0; kk < 2; ++kk) {
      int r = wm * 64 + i * 16 + lr;
      int cidx = kk * 4 + quad;
      aoffs[i][kk] = (r * 8 + (cidx ^ (r & 7))) * 8;
    }
#pragma unroll
  for (int jn = 0; jn < 2; ++jn)
#pragma unroll
    for (int kk = 0; kk < 2; ++kk) {
      int rb = wn * 32 + jn * 16 + lr;
      int cidx = kk * 4 + quad;
      boffs[jn][kk] = (rb * 8 + (cidx ^ (rb & 7))) * 8;
    }

  f32x4 acc[4][2];
#pragma unroll
  for (int i = 0; i < 4; ++i)
#pragma unroll
    for (int jn = 0; jn < 2; ++jn) acc[i][jn] = (f32x4){0.f, 0.f, 0.f, 0.f};

  for (int tap = 0; tap < 9; ++tap) {
    const int dy = tap / 3 - 1, dx = tap % 3 - 1;
    const long tapA = ((long)dy * Wp2 + dx) * Cin;
    const f16* wt_tap = Wp + (size_t)tap * Cout * Cin - (size_t)(Wp - Wp);  // keep type
    const long tapB = (size_t)tap * Cout * Cin;
    for (int kc = 0; kc < Cin; kc += BK) {
      __syncthreads();  // previous reads done before overwrite
#pragma unroll
      for (int e = 0; e < 4; ++e) LLDS16(gA[e] + tapA + kc, Asm + lAoff[e]);
#pragma unroll
      for (int e = 0; e < 2; ++e) LLDS16(gB[e] + tapB + kc, Bsm + lBoff[e]);
      __syncthreads();  // vmcnt(0) drain inserted by compiler

      f16x8 af[4][2], bf[2][2];
#pragma unroll
      for (int i = 0; i < 4; ++i)
#pragma unroll
        for (int kk = 0; kk < 2; ++kk) af[i][kk] = *(const f16x8*)&Asm[aoffs[i][kk]];
#pragma unroll
      for (int jn = 0; jn < 2; ++jn)
#pragma unroll
        for (int kk = 0; kk < 2; ++kk) bf[jn][kk] = *(const f16x8*)&Bsm[boffs[jn][kk]];
#pragma unroll
      for (int kk = 0; kk < 2; ++kk)
#pragma unroll
        for (int i = 0; i < 4; ++i)
#pragma unroll
          for (int jn = 0; jn < 2; ++jn)
            acc[i][jn] = __builtin_amdgcn_mfma_f32_16x16x32_f16(af[i][kk], bf[jn][kk], acc[i][jn], 0, 0, 0);
    }
  }

  // epilogue: C/D col = co (lr), rows = quad*4 + reg
#pragma unroll
  for (int i = 0; i < 4; ++i) {
    int mg = m0 + wm * 64 + i * 16 + quad * 4;
    int n = mg / HW, p = mg - n * HW;
#pragma unroll
    for (int jn = 0; jn < 2; ++jn) {
      int co = co0 + wn * 32 + jn * 16 + lr;
      float b = bias[co];
      f32x4 v = acc[i][jn];
#pragma unroll
      for (int r = 0; r < 4; ++r) {
        float u = v[r] + b;
        v[r] = (do_lrelu && u < 0.f) ? 0.2f * u : u;
      }
      *(f32x4*)&out[((size_t)n * Cout + co) * HW + p] = v;
    }
  }
}

// ---------------- Haar forward (wt) ----------------
__global__ void wt_kernel(const float* __restrict__ in, float* __restrict__ out,
                          int C, int Ho, int Wo, int total) {
  int idx = blockIdx.x * 256 + threadIdx.x;
  if (idx >= total) return;
  int w = idx % Wo; int t = idx / Wo;
  int h = t % Ho; t /= Ho;
  int c = t % C; int n = t / C;
  int Wi = 2 * Wo;
  const float* ip = in + (((size_t)n * C + c) * (2 * Ho) + 2 * h) * Wi + 2 * w;
  float a = ip[0], b = ip[1], cc = ip[Wi], d = ip[Wi + 1];
  size_t cs = (size_t)Ho * Wo;
  float* op = out + (((size_t)n * 4 * C + 4 * c) * Ho + h) * Wo + w;
  op[0]      = 0.25f * (a + b + cc + d);
  op[cs]     = 0.25f * (a + b - cc - d) + 0.5f;
  op[2 * cs] = 0.25f * (a - b + cc - d) + 0.5f;
  op[3 * cs] = 0.25f * (a - b - cc + d) + 0.5f;
}

// ---------------- Haar inverse (iwt) ----------------
__global__ void iwt_kernel(const float* __restrict__ v, float* __restrict__ out,
                           int C, int H, int W, int c_off, int Ctot, int total) {
  int idx = blockIdx.x * 256 + threadIdx.x;
  if (idx >= total) return;
  int w = idx % W; int t = idx / W;
  int h = t % H; t /= H;
  int c = t % C; int n = t / C;
  size_t cs = (size_t)H * W;
  const float* vp = v + (((size_t)n * 4 * C + 4 * c) * H + h) * W + w;
  float v0 = vp[0];
  float v1 = 2.f * vp[cs] - 1.f;
  float v2 = 2.f * vp[2 * cs] - 1.f;
  float v3 = 2.f * vp[3 * cs] - 1.f;
  int Wo = 2 * W;
  float* op = out + (((size_t)n * Ctot + c_off + c) * (2 * H) + 2 * h) * (size_t)Wo + 2 * w;
  op[0]      = v0 + 0.5f * ( v1 + v2 + v3);
  op[1]      = v0 + 0.5f * ( v1 - v2 - v3);
  op[Wo]     = v0 + 0.5f * (-v1 + v2 - v3);
  op[Wo + 1] = v0 + 0.5f * (-v1 - v2 + v3);
}

// ---------------- concat first-part copy ----------------
__global__ void copycat_kernel(const float* __restrict__ src, float* __restrict__ dst,
                               int C, int HW, int Ctot, int total) {
  int idx = blockIdx.x * 256 + threadIdx.x;
  if (idx >= total) return;
  int p = idx % HW; int t = idx / HW;
  int c = t % C; int n = t / C;
  dst[((size_t)n * Ctot + c) * HW + p] = src[idx];
}

// ---------------- a = lrelu(a + b) ----------------
__global__ void addlrelu_kernel(float* __restrict__ a, const float* __restrict__ b, int total) {
  int idx = blockIdx.x * 256 + threadIdx.x;
  if (idx >= total) return;
  float v = a[idx] + b[idx];
  a[idx] = v > 0.f ? v : 0.2f * v;
}

// ---------------- direct 3x3 conv (small channel counts) ----------------
template <int CO, int CIC>
__global__ __launch_bounds__(256) void conv3x3_kernel(
    const float* __restrict__ in, const float* __restrict__ wgt,
    const float* __restrict__ bias, float* __restrict__ out,
    int Cin, int H, int W, int Cout, int do_lrelu) {
  __shared__ float sm[CIC][18][18];
  int tiles_x = W >> 4;
  int bt = blockIdx.x;
  int tx0 = (bt % tiles_x) << 4;
  int ty0 = (bt / tiles_x) << 4;
  int co0 = blockIdx.y * CO;
  int n = blockIdx.z;
  int tid = threadIdx.x;
  int lx = tid & 15, ly = tid >> 4;

  float acc[CO];
#pragma unroll
  for (int i = 0; i < CO; i++) acc[i] = 0.f;

  const float* inb = in + (size_t)n * Cin * H * W;

  for (int ci0 = 0; ci0 < Cin; ci0 += CIC) {
    __syncthreads();
    for (int idx = tid; idx < CIC * 324; idx += 256) {
      int ci = idx / 324;
      int r = idx - ci * 324;
      int gy = r / 18, gx = r - gy * 18;
      int iy = ty0 + gy - 1, ix = tx0 + gx - 1;
      float v = 0.f;
      if ((unsigned)iy < (unsigned)H && (unsigned)ix < (unsigned)W)
        v = inb[((size_t)(ci0 + ci)) * H * W + (size_t)iy * W + ix];
      sm[ci][gy][gx] = v;
    }
    __syncthreads();
#pragma unroll
    for (int ci = 0; ci < CIC; ci++) {
      float x00 = sm[ci][ly][lx],     x01 = sm[ci][ly][lx + 1],     x02 = sm[ci][ly][lx + 2];
      float x10 = sm[ci][ly + 1][lx], x11 = sm[ci][ly + 1][lx + 1], x12 = sm[ci][ly + 1][lx + 2];
      float x20 = sm[ci][ly + 2][lx], x21 = sm[ci][ly + 2][lx + 1], x22 = sm[ci][ly + 2][lx + 2];
      const float* wp = wgt + ((size_t)co0 * Cin + (ci0 + ci)) * 9;
#pragma unroll
      for (int co = 0; co < CO; co++) {
        const float* wc = wp + (size_t)co * Cin * 9;
        float a = acc[co];
        a = fmaf(wc[0], x00, a); a = fmaf(wc[1], x01, a); a = fmaf(wc[2], x02, a);
        a = fmaf(wc[3], x10, a); a = fmaf(wc[4], x11, a); a = fmaf(wc[5], x12, a);
        a = fmaf(wc[6], x20, a); a = fmaf(wc[7], x21, a); a = fmaf(wc[8], x22, a);
        acc[co] = a;
      }
    }
  }

  int oy = ty0 + ly, ox = tx0 + lx;
#pragma unroll
  for (int co = 0; co < CO; co++) {
    float v = acc[co] + bias[co0 + co];
    if (do_lrelu) v = v > 0.f ? v : 0.2f * v;
    out[(((size_t)n * Cout + co0 + co) * H + oy) * W + ox] = v;
  }
}

// ---------------- group norm (in place) ----------------
__global__ void gn_kernel(float* __restrict__ x, const float* __restrict__ gamma,
                          const float* __restrict__ beta, int C, int HW, int G) {
  __shared__ float red[512];
  int gr = blockIdx.x, n = blockIdx.y;
  int cpg = C / G;
  size_t base = ((size_t)n * C + (size_t)gr * cpg) * HW;
  int len = cpg * HW;
  float s = 0.f, s2 = 0.f;
  for (int i = threadIdx.x; i < len; i += 256) { float v = x[base + i]; s += v; s2 += v * v; }
  red[threadIdx.x] = s; red[256 + threadIdx.x] = s2;
  __syncthreads();
  for (int st = 128; st > 0; st >>= 1) {
    if (threadIdx.x < st) {
      red[threadIdx.x] += red[threadIdx.x + st];
      red[256 + threadIdx.x] += red[256 + threadIdx.x + st];
    }
    __syncthreads();
  }
  float mean = red[0] / (float)len;
  float var = red[256] / (float)len - mean * mean;
  if (var < 0.f) var = 0.f;
  float inv = rsqrtf(var + 1e-5f);
  for (int i = threadIdx.x; i < len; i += 256) {
    int c = i / HW;
    float v = (x[base + i] - mean) * inv;
    x[base + i] = v * gamma[gr * cpg + c] + beta[gr * cpg + c];
  }
}

// ---------------- final 1x1 conv ----------------
__global__ void final_conv_kernel(const float* __restrict__ in, const float* __restrict__ w,
                                  float* __restrict__ out, int HW, int total) {
  int idx = blockIdx.x * 256 + threadIdx.x;
  if (idx >= total) return;
  int p = idx % HW; int n = idx / HW;
  const float* ip = in + (size_t)n * 3 * HW + p;
  float a = ip[0], b = ip[HW], c = ip[2 * (size_t)HW];
  float* op = out + (size_t)n * 2 * HW + p;
  op[0]  = w[0] * a + w[1] * b + w[2] * c;
  op[HW] = w[3] * a + w[4] * b + w[5] * c;
}

// ---------------------------------------------------------------------------

extern "C" void kernel_launch(void* const* d_in, const int* in_sizes, int n_in,
                              void* d_out, int out_size, void* d_ws, size_t ws_size,
                              hipStream_t stream) {
  const float* x        = (const float*)d_in[0];
  const float* conv1_w  = (const float*)d_in[1];
  const float* conv1_b  = (const float*)d_in[2];
  const float* conv2_w  = (const float*)d_in[3];
  const float* conv2_b  = (const float*)d_in[4];
  const float* conv3_w  = (const float*)d_in[5];
  const float* conv3_b  = (const float*)d_in[6];
  const float* conv4_w  = (const float*)d_in[7];
  const float* conv4_b  = (const float*)d_in[8];
  const float* convd1_w = (const float*)d_in[9];
  const float* convd1_b = (const float*)d_in[10];
  const float* convd2_w = (const float*)d_in[11];
  const float* convd2_b = (const float*)d_in[12];
  const float* convd3_w = (const float*)d_in[13];
  const float* convd3_b = (const float*)d_in[14];
  const float* convd4_w = (const float*)d_in[15];
  const float* convd4_b = (const float*)d_in[16];
  const float* final_w  = (const float*)d_in[17];
  const float* gn1_w = (const float*)d_in[18];
  const float* gn1_b = (const float*)d_in[19];
  const float* gn2_w = (const float*)d_in[20];
  const float* gn2_b = (const float*)d_in[21];
  const float* gn3_w = (const float*)d_in[22];
  const float* gn3_b = (const float*)d_in[23];
  const float* gn4_w = (const float*)d_in[24];
  const float* gn4_b = (const float*)d_in[25];

  char* base = (char*)d_ws;
  size_t off = 0;
  auto allocB = [&](size_t bytes) { size_t o = off; off = (off + bytes + 255) & ~(size_t)255; return o; };

  // fp32 standardized weights (direct convs)
  size_t o_sw1  = allocB(16 * 108 * 4);
  size_t o_swd1 = allocB(12 * 144 * 4);
  size_t o_swd2 = allocB(16 * 288 * 4);
  size_t o_swf  = allocB(6 * 4);
  // f16 packed weights [tap][Cout][Cin]
  size_t o_pw2  = allocB((size_t)9 * 64 * 64 * 2);
  size_t o_pw3  = allocB((size_t)9 * 256 * 256 * 2);
  size_t o_pw4  = allocB((size_t)9 * 1024 * 1024 * 2);
  size_t o_pwd3 = allocB((size_t)9 * 64 * 128 * 2);
  size_t o_pwd4 = allocB((size_t)9 * 256 * 512 * 2);
  // padded NHWC f16 activation mirror (max: 16*34*34*512 halves)
  size_t o_ah   = allocB((size_t)16 * 34 * 34 * 512 * 2);
  // fp32 activations
  size_t o_c1 = allocB((size_t)NB * 16 * 128 * 128 * 4);
  size_t o_c2 = allocB((size_t)NB * 64 * 64 * 64 * 4);
  size_t o_c3 = allocB((size_t)NB * 256 * 32 * 32 * 4);
  size_t o_w4 = allocB((size_t)NB * 1024 * 16 * 16 * 4);
  size_t o_t1 = allocB((size_t)NB * 1024 * 16 * 16 * 4);
  size_t o_t2 = allocB((size_t)NB * 512 * 32 * 32 * 4);

  if (off > ws_size) return;

  float* c1 = (float*)(base + o_c1);
  float* c2 = (float*)(base + o_c2);
  float* c3 = (float*)(base + o_c3);
  float* w4 = (float*)(base + o_w4);
  float* t1 = (float*)(base + o_t1);
  float* t2 = (float*)(base + o_t2);
  f16* ah = (f16*)(base + o_ah);
  f16* pw2 = (f16*)(base + o_pw2);
  f16* pw3 = (f16*)(base + o_pw3);
  f16* pw4 = (f16*)(base + o_pw4);
  f16* pwd3 = (f16*)(base + o_pwd3);
  f16* pwd4 = (f16*)(base + o_pwd4);

  // ---- weight prep ----
  ws_kernel<<<16, 256, 0, stream>>>(conv1_w,  (float*)(base + o_sw1),  108);
  ws_kernel<<<12, 256, 0, stream>>>(convd1_w, (float*)(base + o_swd1), 144);
  ws_kernel<<<16, 256, 0, stream>>>(convd2_w, (float*)(base + o_swd2), 288);
  ws_kernel<<<2,  256, 0, stream>>>(final_w,  (float*)(base + o_swf),  3);
  ws_f16_kernel<<<64,   256, 0, stream>>>(conv2_w,  pw2,  576,  64,   64);
  ws_f16_kernel<<<256,  256, 0, stream>>>(conv3_w,  pw3,  2304, 256,  256);
  ws_f16_kernel<<<1024, 256, 0, stream>>>(conv4_w,  pw4,  9216, 1024, 1024);
  ws_f16_kernel<<<64,   256, 0, stream>>>(convd3_w, pwd3, 1152, 128,  64);
  ws_f16_kernel<<<256,  256, 0, stream>>>(convd4_w, pwd4, 4608, 512,  256);

  auto launch_wt = [&](const float* in, float* out, int C, int Ho, int Wo) {
    int total = NB * C * Ho * Wo;
    wt_kernel<<<(total + 255) / 256, 256, 0, stream>>>(in, out, C, Ho, Wo, total);
  };
  auto prep_nhwc = [&](const float* in, int C, int H, int W) {
    int total8 = NB * (2 * (W + 2) + 2 * H) * (C / 8);
    zero_halo_kernel<<<(total8 + 255) / 256, 256, 0, stream>>>(ah, C, H, W, total8);
    dim3 g((H * W) / 256, C / 32, NB);
    to_nhwc_pad_kernel<<<g, 256, 0, stream>>>(in, ah, C, H, W);
  };
  auto launch_cmfma = [&](const f16* w, const float* b, float* o,
                          int Cin, int Hs, int Ws, int Cout, int lr) {
    dim3 g((NB * Hs * Ws) / 128, Cout / 64);
    conv_mfma2_kernel<<<g, 256, 0, stream>>>(ah, w, b, o, Cin, Hs, Ws, Cout, Hs * Ws, lr);
  };
  auto launch_conv = [&](const float* in, const float* w, const float* b, float* out,
                         int Cin, int H, int W, int Cout, int lrelu) {
    dim3 g((W / 16) * (H / 16), Cout / 4, NB);
    conv3x3_kernel<4, 4><<<g, 256, 0, stream>>>(in, w, b, out, Cin, H, W, Cout, lrelu);
  };
  auto launch_gn = [&](float* xb, const float* g, const float* b, int C, int HW, int G) {
    dim3 gr(G, NB);
    gn_kernel<<<gr, 256, 0, stream>>>(xb, g, b, C, HW, G);
  };
  auto launch_iwt = [&](const float* v, float* out, int C, int H, int W, int c_off, int Ctot) {
    int total = NB * C * H * W;
    iwt_kernel<<<(total + 255) / 256, 256, 0, stream>>>(v, out, C, H, W, c_off, Ctot, total);
  };
  auto launch_copycat = [&](const float* src, float* dst, int C, int HW, int Ctot) {
    int total = NB * C * HW;
    copycat_kernel<<<(total + 255) / 256, 256, 0, stream>>>(src, dst, C, HW, Ctot, total);
  };

  // ---- encoder ----
  launch_wt(x, t1, 3, 128, 128);                                   // w1 (16,12,128,128)
  launch_conv(t1, (float*)(base + o_sw1), conv1_b, c1, 12, 128, 128, 16, 1);
  launch_gn(c1, gn1_w, gn1_b, 16, 128 * 128, 2);

  launch_wt(c1, t1, 16, 64, 64);                                   // w2 (16,64,64,64)
  prep_nhwc(t1, 64, 64, 64);
  launch_cmfma(pw2, conv2_b, c2, 64, 64, 64, 64, 1);               // c2
  launch_gn(c2, gn2_w, gn2_b, 64, 64 * 64, 8);

  launch_wt(c2, t1, 64, 32, 32);                                   // w3 (16,256,32,32)
  prep_nhwc(t1, 256, 32, 32);
  launch_cmfma(pw3, conv3_b, c3, 256, 32, 32, 256, 1);             // c3
  launch_gn(c3, gn3_w, gn3_b, 256, 32 * 32, 32);

  launch_wt(c3, w4, 256, 16, 16);                                  // w4 (16,1024,16,16)

  prep_nhwc(w4, 1024, 16, 16);
  launch_cmfma(pw4, conv4_b, t1, 1024, 16, 16, 1024, 1);           // c4 -> t1
  launch_gn(t1, gn4_w, gn4_b, 1024, 16 * 16, 128);
  prep_nhwc(t1, 1024, 16, 16);
  launch_cmfma(pw4, conv4_b, t2, 1024, 16, 16, 1024, 1);           // c5 -> t2
  launch_gn(t2, gn4_w, gn4_b, 1024, 16 * 16, 128);
  prep_nhwc(t2, 1024, 16, 16);
  launch_cmfma(pw4, conv4_b, t1, 1024, 16, 16, 1024, 0);           // c6 -> t1

  {  // ic4 = lrelu(c6 + w4) in t1
    int total = NB * 1024 * 16 * 16;
    addlrelu_kernel<<<(total + 255) / 256, 256, 0, stream>>>(t1, w4, total);
  }

  // ---- decoder ----
  launch_copycat(c3, t2, 256, 32 * 32, 512);                       // iw4 -> t2
  launch_iwt(t1, t2, 256, 16, 16, 256, 512);
  prep_nhwc(t2, 512, 32, 32);
  launch_cmfma(pwd4, convd4_b, t1, 512, 32, 32, 256, 1);           // ic3 -> t1
  launch_gn(t1, gn3_w, gn3_b, 256, 32 * 32, 32);

  launch_copycat(c2, t2, 64, 64 * 64, 128);                        // iw3 -> t2
  launch_iwt(t1, t2, 64, 32, 32, 64, 128);
  prep_nhwc(t2, 128, 64, 64);
  launch_cmfma(pwd3, convd3_b, t1, 128, 64, 64, 64, 1);            // ic2 -> t1
  launch_gn(t1, gn2_w, gn2_b, 64, 64 * 64, 8);

  launch_copycat(c1, t2, 16, 128 * 128, 32);                       // iw2 -> t2
  launch_iwt(t1, t2, 16, 64, 64, 16, 32);
  launch_conv(t2, (float*)(base + o_swd2), convd2_b, t1, 32, 128, 128, 16, 1);  // ic1
  launch_gn(t1, gn1_w, gn1_b, 16, 128 * 128, 2);

  launch_conv(t1, (float*)(base + o_swd1), convd1_b, t2, 16, 128, 128, 12, 1);  // iw1

  launch_iwt(t2, t1, 3, 128, 128, 0, 3);                           // iwt(iw1) (16,3,256,256)

  {  // final 1x1
    int total = NB * 256 * 256;
    final_conv_kernel<<<(total + 255) / 256, 256, 0, stream>>>(t1, (float*)(base + o_swf),
                                                               (float*)d_out, 256 * 256, total);
  }
}

// Round 4
// 1146.749 us; speedup vs baseline: 9.5358x; 1.3411x over previous
//
#include <hip/hip_runtime.h>
#include <math.h>

// ---------------------------------------------------------------------------
// WaveletNet forward. Big convs via f16 MFMA implicit GEMM (tap-wise) with
// global_load_lds async staging from a zero-halo-padded NHWC f16 mirror.
// Small convs direct fp32. GroupNorm as split 3-kernel (stats/combine/apply).
// N=16 fixed.
// ---------------------------------------------------------------------------

#define NB 16  // batch

typedef _Float16 f16;
typedef _Float16 f16x8 __attribute__((ext_vector_type(8)));
typedef float f32x4 __attribute__((ext_vector_type(4)));
typedef unsigned int u32;

// async global->LDS 16B: lds dest must be wave-uniform base (+lane*16 by HW)
#define LLDS16(gp, lp)                                                          \
  __builtin_amdgcn_global_load_lds((const __attribute__((address_space(1))) u32*)(const void*)(gp), \
                                   (__attribute__((address_space(3))) u32*)(void*)(lp), 16, 0, 0)

// ---------------- weight standardization (fp32 out, for direct convs) -------
__global__ void ws_kernel(const float* __restrict__ w, float* __restrict__ out, int fan) {
  __shared__ float red[512];
  int o = blockIdx.x;
  const float* wp = w + (size_t)o * fan;
  float s = 0.f, s2 = 0.f;
  for (int i = threadIdx.x; i < fan; i += 256) { float v = wp[i]; s += v; s2 += v * v; }
  red[threadIdx.x] = s; red[256 + threadIdx.x] = s2;
  __syncthreads();
  for (int st = 128; st > 0; st >>= 1) {
    if (threadIdx.x < st) {
      red[threadIdx.x] += red[threadIdx.x + st];
      red[256 + threadIdx.x] += red[256 + threadIdx.x + st];
    }
    __syncthreads();
  }
  float sum = red[0], sumsq = red[256];
  float mean = sum / (float)fan;
  float var = (sumsq - sum * mean) / (float)(fan - 1);
  if (var < 0.f) var = 0.f;
  float inv = 1.0f / (sqrtf(var) + 1e-5f);
  for (int i = threadIdx.x; i < fan; i += 256)
    out[(size_t)o * fan + i] = (wp[i] - mean) * inv;
}

// ---------------- weight standardization + f16 pack [tap][Cout][Cin] --------
__global__ void ws_f16_kernel(const float* __restrict__ w, f16* __restrict__ out,
                              int fan, int Cin, int Cout) {
  __shared__ float red[512];
  int o = blockIdx.x;
  const float* wp = w + (size_t)o * fan;
  float s = 0.f, s2 = 0.f;
  for (int i = threadIdx.x; i < fan; i += 256) { float v = wp[i]; s += v; s2 += v * v; }
  red[threadIdx.x] = s; red[256 + threadIdx.x] = s2;
  __syncthreads();
  for (int st = 128; st > 0; st >>= 1) {
    if (threadIdx.x < st) {
      red[threadIdx.x] += red[threadIdx.x + st];
      red[256 + threadIdx.x] += red[256 + threadIdx.x + st];
    }
    __syncthreads();
  }
  float sum = red[0], sumsq = red[256];
  float mean = sum / (float)fan;
  float var = (sumsq - sum * mean) / (float)(fan - 1);
  if (var < 0.f) var = 0.f;
  float inv = 1.0f / (sqrtf(var) + 1e-5f);
  for (int i = threadIdx.x; i < fan; i += 256) {
    int ci = i / 9, tap = i - ci * 9;
    out[((size_t)tap * Cout + o) * Cin + ci] = (f16)((wp[i] - mean) * inv);
  }
}

// ---------------- zero the 1-px halo of a padded NHWC f16 buffer ------------
__global__ void zero_halo_kernel(f16* __restrict__ buf, int C, int H, int W, int total8) {
  int idx = blockIdx.x * 256 + threadIdx.x;
  if (idx >= total8) return;
  int c8s = C >> 3;
  int c8 = idx % c8s; int t = idx / c8s;
  int P = 2 * (W + 2) + 2 * H;
  int b = t % P; int n = t / P;
  int y, x;
  if (b < W + 2) { y = 0; x = b; }
  else if (b < 2 * (W + 2)) { y = H + 1; x = b - (W + 2); }
  else { int bb = b - 2 * (W + 2); y = 1 + (bb >> 1); x = (bb & 1) ? (W + 1) : 0; }
  size_t a = (((size_t)n * (H + 2) + y) * (W + 2) + x) * C + c8 * 8;
  f16x8 z = {0, 0, 0, 0, 0, 0, 0, 0};
  *(f16x8*)(buf + a) = z;
}

// ---------------- NCHW fp32 -> padded NHWC f16 transpose ----------------
__global__ __launch_bounds__(256) void to_nhwc_pad_kernel(const float* __restrict__ in,
                                                          f16* __restrict__ out,
                                                          int C, int H, int W) {
  __shared__ f16 sm[32][264];
  int HW = H * W;
  int p0 = blockIdx.x * 256, c0 = blockIdx.y * 32, n = blockIdx.z;
  int t = threadIdx.x;
  const float* ip = in + ((size_t)n * C + c0) * HW + p0;
#pragma unroll 8
  for (int r = 0; r < 32; ++r) sm[r][t] = (f16)ip[(size_t)r * HW + t];
  __syncthreads();
#pragma unroll
  for (int i = 0; i < 4; ++i) {
    int c = t + i * 256;
    int pl = c >> 2, cio = (c & 3) * 8;
    f16x8 v;
#pragma unroll
    for (int u = 0; u < 8; ++u) v[u] = sm[cio + u][pl];
    int p = p0 + pl; int y = p / W; int x = p - y * W;
    *(f16x8*)(out + (((size_t)n * (H + 2) + y + 1) * (W + 2) + x + 1) * C + c0 + cio) = v;
  }
}

// ---------------- MFMA implicit-GEMM 3x3 conv, v2 ----------------
__global__ __launch_bounds__(256) void conv_mfma2_kernel(
    const f16* __restrict__ A, const f16* __restrict__ Wp,
    const float* __restrict__ bias, float* __restrict__ out,
    int Cin, int H, int W, int Cout, int HW, int do_lrelu) {
  constexpr int BM = 128, BN = 64, BK = 64;
  __shared__ f16 Asm[BM * BK];  // 16 KB
  __shared__ f16 Bsm[BN * BK];  // 8 KB

  const int tid = threadIdx.x;
  const int w = tid >> 6, lane = tid & 63;
  const int m0 = blockIdx.x * BM;
  const int co0 = blockIdx.y * BN;
  const int Wp2 = W + 2;

  const f16* gA[4];
  int lAoff[4];
#pragma unroll
  for (int e = 0; e < 4; ++e) {
    int c = e * 256 + tid;
    int r = c >> 3, j = c & 7;
    int jx = j ^ (r & 7);
    int m = m0 + r; int n = m / HW; int p = m - n * HW;
    int y = p / W; int x = p - y * W;
    gA[e] = A + (((size_t)n * (H + 2) + y + 1) * Wp2 + (x + 1)) * Cin + jx * 8;
    lAoff[e] = (e * 256 + w * 64) * 8;
  }
  const f16* gB[2];
  int lBoff[2];
#pragma unroll
  for (int e = 0; e < 2; ++e) {
    int c = e * 256 + tid;
    int r = c >> 3, j = c & 7;
    int jx = j ^ (r & 7);
    gB[e] = Wp + (size_t)(co0 + r) * Cin + jx * 8;
    lBoff[e] = (e * 256 + w * 64) * 8;
  }

  const int wm = w & 1, wn = w >> 1;
  const int lr = lane & 15, quad = lane >> 4;
  int aoffs[4][2], boffs[2][2];
#pragma unroll
  for (int i = 0; i < 4; ++i)
#pragma unroll
    for (int kk = 0; kk < 2; ++kk) {
      int r = wm * 64 + i * 16 + lr;
      int cidx = kk * 4 + quad;
      aoffs[i][kk] = (r * 8 + (cidx ^ (r & 7))) * 8;
    }
#pragma unroll
  for (int jn = 0; jn < 2; ++jn)
#pragma unroll
    for (int kk = 0; kk < 2; ++kk) {
      int rb = wn * 32 + jn * 16 + lr;
      int cidx = kk * 4 + quad;
      boffs[jn][kk] = (rb * 8 + (cidx ^ (rb & 7))) * 8;
    }

  f32x4 acc[4][2];
#pragma unroll
  for (int i = 0; i < 4; ++i)
#pragma unroll
    for (int jn = 0; jn < 2; ++jn) acc[i][jn] = (f32x4){0.f, 0.f, 0.f, 0.f};

  for (int tap = 0; tap < 9; ++tap) {
    const int dy = tap / 3 - 1, dx = tap % 3 - 1;
    const long tapA = ((long)dy * Wp2 + dx) * Cin;
    const long tapB = (size_t)tap * Cout * Cin;
    for (int kc = 0; kc < Cin; kc += BK) {
      __syncthreads();
#pragma unroll
      for (int e = 0; e < 4; ++e) LLDS16(gA[e] + tapA + kc, Asm + lAoff[e]);
#pragma unroll
      for (int e = 0; e < 2; ++e) LLDS16(gB[e] + tapB + kc, Bsm + lBoff[e]);
      __syncthreads();

      f16x8 af[4][2], bf[2][2];
#pragma unroll
      for (int i = 0; i < 4; ++i)
#pragma unroll
        for (int kk = 0; kk < 2; ++kk) af[i][kk] = *(const f16x8*)&Asm[aoffs[i][kk]];
#pragma unroll
      for (int jn = 0; jn < 2; ++jn)
#pragma unroll
        for (int kk = 0; kk < 2; ++kk) bf[jn][kk] = *(const f16x8*)&Bsm[boffs[jn][kk]];
#pragma unroll
      for (int kk = 0; kk < 2; ++kk)
#pragma unroll
        for (int i = 0; i < 4; ++i)
#pragma unroll
          for (int jn = 0; jn < 2; ++jn)
            acc[i][jn] = __builtin_amdgcn_mfma_f32_16x16x32_f16(af[i][kk], bf[jn][kk], acc[i][jn], 0, 0, 0);
    }
  }

#pragma unroll
  for (int i = 0; i < 4; ++i) {
    int mg = m0 + wm * 64 + i * 16 + quad * 4;
    int n = mg / HW, p = mg - n * HW;
#pragma unroll
    for (int jn = 0; jn < 2; ++jn) {
      int co = co0 + wn * 32 + jn * 16 + lr;
      float b = bias[co];
      f32x4 v = acc[i][jn];
#pragma unroll
      for (int r = 0; r < 4; ++r) {
        float u = v[r] + b;
        v[r] = (do_lrelu && u < 0.f) ? 0.2f * u : u;
      }
      *(f32x4*)&out[((size_t)n * Cout + co) * HW + p] = v;
    }
  }
}

// ---------------- Haar forward (wt) ----------------
__global__ void wt_kernel(const float* __restrict__ in, float* __restrict__ out,
                          int C, int Ho, int Wo, int total) {
  int idx = blockIdx.x * 256 + threadIdx.x;
  if (idx >= total) return;
  int w = idx % Wo; int t = idx / Wo;
  int h = t % Ho; t /= Ho;
  int c = t % C; int n = t / C;
  int Wi = 2 * Wo;
  const float* ip = in + (((size_t)n * C + c) * (2 * Ho) + 2 * h) * Wi + 2 * w;
  float a = ip[0], b = ip[1], cc = ip[Wi], d = ip[Wi + 1];
  size_t cs = (size_t)Ho * Wo;
  float* op = out + (((size_t)n * 4 * C + 4 * c) * Ho + h) * Wo + w;
  op[0]      = 0.25f * (a + b + cc + d);
  op[cs]     = 0.25f * (a + b - cc - d) + 0.5f;
  op[2 * cs] = 0.25f * (a - b + cc - d) + 0.5f;
  op[3 * cs] = 0.25f * (a - b - cc + d) + 0.5f;
}

// ---------------- Haar inverse (iwt) ----------------
__global__ void iwt_kernel(const float* __restrict__ v, float* __restrict__ out,
                           int C, int H, int W, int c_off, int Ctot, int total) {
  int idx = blockIdx.x * 256 + threadIdx.x;
  if (idx >= total) return;
  int w = idx % W; int t = idx / W;
  int h = t % H; t /= H;
  int c = t % C; int n = t / C;
  size_t cs = (size_t)H * W;
  const float* vp = v + (((size_t)n * 4 * C + 4 * c) * H + h) * W + w;
  float v0 = vp[0];
  float v1 = 2.f * vp[cs] - 1.f;
  float v2 = 2.f * vp[2 * cs] - 1.f;
  float v3 = 2.f * vp[3 * cs] - 1.f;
  int Wo = 2 * W;
  float* op = out + (((size_t)n * Ctot + c_off + c) * (2 * H) + 2 * h) * (size_t)Wo + 2 * w;
  op[0]      = v0 + 0.5f * ( v1 + v2 + v3);
  op[1]      = v0 + 0.5f * ( v1 - v2 - v3);
  op[Wo]     = v0 + 0.5f * (-v1 + v2 - v3);
  op[Wo + 1] = v0 + 0.5f * (-v1 - v2 + v3);
}

// ---------------- concat first-part copy ----------------
__global__ void copycat_kernel(const float* __restrict__ src, float* __restrict__ dst,
                               int C, int HW, int Ctot, int total) {
  int idx = blockIdx.x * 256 + threadIdx.x;
  if (idx >= total) return;
  int p = idx % HW; int t = idx / HW;
  int c = t % C; int n = t / C;
  dst[((size_t)n * Ctot + c) * HW + p] = src[idx];
}

// ---------------- a = lrelu(a + b) ----------------
__global__ void addlrelu_kernel(float* __restrict__ a, const float* __restrict__ b, int total) {
  int idx = blockIdx.x * 256 + threadIdx.x;
  if (idx >= total) return;
  float v = a[idx] + b[idx];
  a[idx] = v > 0.f ? v : 0.2f * v;
}

// ---------------- direct 3x3 conv (small channel counts) ----------------
template <int CO, int CIC>
__global__ __launch_bounds__(256) void conv3x3_kernel(
    const float* __restrict__ in, const float* __restrict__ wgt,
    const float* __restrict__ bias, float* __restrict__ out,
    int Cin, int H, int W, int Cout, int do_lrelu) {
  __shared__ float sm[CIC][18][18];
  int tiles_x = W >> 4;
  int bt = blockIdx.x;
  int tx0 = (bt % tiles_x) << 4;
  int ty0 = (bt / tiles_x) << 4;
  int co0 = blockIdx.y * CO;
  int n = blockIdx.z;
  int tid = threadIdx.x;
  int lx = tid & 15, ly = tid >> 4;

  float acc[CO];
#pragma unroll
  for (int i = 0; i < CO; i++) acc[i] = 0.f;

  const float* inb = in + (size_t)n * Cin * H * W;

  for (int ci0 = 0; ci0 < Cin; ci0 += CIC) {
    __syncthreads();
    for (int idx = tid; idx < CIC * 324; idx += 256) {
      int ci = idx / 324;
      int r = idx - ci * 324;
      int gy = r / 18, gx = r - gy * 18;
      int iy = ty0 + gy - 1, ix = tx0 + gx - 1;
      float v = 0.f;
      if ((unsigned)iy < (unsigned)H && (unsigned)ix < (unsigned)W)
        v = inb[((size_t)(ci0 + ci)) * H * W + (size_t)iy * W + ix];
      sm[ci][gy][gx] = v;
    }
    __syncthreads();
#pragma unroll
    for (int ci = 0; ci < CIC; ci++) {
      float x00 = sm[ci][ly][lx],     x01 = sm[ci][ly][lx + 1],     x02 = sm[ci][ly][lx + 2];
      float x10 = sm[ci][ly + 1][lx], x11 = sm[ci][ly + 1][lx + 1], x12 = sm[ci][ly + 1][lx + 2];
      float x20 = sm[ci][ly + 2][lx], x21 = sm[ci][ly + 2][lx + 1], x22 = sm[ci][ly + 2][lx + 2];
      const float* wp = wgt + ((size_t)co0 * Cin + (ci0 + ci)) * 9;
#pragma unroll
      for (int co = 0; co < CO; co++) {
        const float* wc = wp + (size_t)co * Cin * 9;
        float a = acc[co];
        a = fmaf(wc[0], x00, a); a = fmaf(wc[1], x01, a); a = fmaf(wc[2], x02, a);
        a = fmaf(wc[3], x10, a); a = fmaf(wc[4], x11, a); a = fmaf(wc[5], x12, a);
        a = fmaf(wc[6], x20, a); a = fmaf(wc[7], x21, a); a = fmaf(wc[8], x22, a);
        acc[co] = a;
      }
    }
  }

  int oy = ty0 + ly, ox = tx0 + lx;
#pragma unroll
  for (int co = 0; co < CO; co++) {
    float v = acc[co] + bias[co0 + co];
    if (do_lrelu) v = v > 0.f ? v : 0.2f * v;
    out[(((size_t)n * Cout + co0 + co) * H + oy) * W + ox] = v;
  }
}

// ---------------- group norm: split 3-kernel ----------------
// stats: grid (G*SPLIT, NB); each block reduces a chunk of len/SPLIT elems.
__global__ __launch_bounds__(256) void gn_stats_kernel(const float* __restrict__ x,
                                                       float* __restrict__ part,
                                                       int C, int HW, int G, int SPLIT) {
  __shared__ float red[512];
  int gs = blockIdx.x;
  int g = gs / SPLIT, s = gs - g * SPLIT;
  int n = blockIdx.y;
  int cpg = C / G;
  int len = cpg * HW;
  int chunk = len / SPLIT;
  size_t base = ((size_t)n * C + (size_t)g * cpg) * HW + (size_t)s * chunk;
  const f32x4* xp = (const f32x4*)(x + base);
  int chunk4 = chunk >> 2;
  float sm = 0.f, s2 = 0.f;
  for (int i = threadIdx.x; i < chunk4; i += 256) {
    f32x4 v = xp[i];
    sm += v.x + v.y + v.z + v.w;
    s2 += v.x * v.x + v.y * v.y + v.z * v.z + v.w * v.w;
  }
  red[threadIdx.x] = sm; red[256 + threadIdx.x] = s2;
  __syncthreads();
  for (int st = 128; st > 0; st >>= 1) {
    if (threadIdx.x < st) {
      red[threadIdx.x] += red[threadIdx.x + st];
      red[256 + threadIdx.x] += red[256 + threadIdx.x + st];
    }
    __syncthreads();
  }
  if (threadIdx.x == 0) {
    int o = ((n * G + g) * SPLIT + s) * 2;
    part[o] = red[0]; part[o + 1] = red[256];
  }
}

// combine: one thread per (n,g)
__global__ void gn_combine_kernel(const float* __restrict__ part, float* __restrict__ stats,
                                  int SPLIT, int len, int total) {
  int idx = blockIdx.x * 256 + threadIdx.x;
  if (idx >= total) return;
  float s = 0.f, s2 = 0.f;
  for (int i = 0; i < SPLIT; ++i) { s += part[(idx * SPLIT + i) * 2]; s2 += part[(idx * SPLIT + i) * 2 + 1]; }
  float mean = s / (float)len;
  float var = s2 / (float)len - mean * mean;
  if (var < 0.f) var = 0.f;
  stats[idx * 2] = mean;
  stats[idx * 2 + 1] = rsqrtf(var + 1e-5f);
}

// apply: float4, in place
__global__ __launch_bounds__(256) void gn_apply_kernel(float* __restrict__ x,
                                                       const float* __restrict__ stats,
                                                       const float* __restrict__ gamma,
                                                       const float* __restrict__ beta,
                                                       int C, int HW, int G, int total4) {
  int idx = blockIdx.x * 256 + threadIdx.x;
  if (idx >= total4) return;
  int hw4 = HW >> 2;
  int p4 = idx % hw4; int t = idx / hw4;
  int c = t % C; int n = t / C;
  int cpg = C / G; int g = c / cpg;
  float mean = stats[(n * G + g) * 2];
  float inv  = stats[(n * G + g) * 2 + 1];
  float ga = gamma[c], be = beta[c];
  f32x4* xp = (f32x4*)(x + ((size_t)t * HW)) + p4;
  f32x4 v = *xp;
#pragma unroll
  for (int r = 0; r < 4; ++r) v[r] = (v[r] - mean) * inv * ga + be;
  *xp = v;
}

// ---------------- final 1x1 conv ----------------
__global__ void final_conv_kernel(const float* __restrict__ in, const float* __restrict__ w,
                                  float* __restrict__ out, int HW, int total) {
  int idx = blockIdx.x * 256 + threadIdx.x;
  if (idx >= total) return;
  int p = idx % HW; int n = idx / HW;
  const float* ip = in + (size_t)n * 3 * HW + p;
  float a = ip[0], b = ip[HW], c = ip[2 * (size_t)HW];
  float* op = out + (size_t)n * 2 * HW + p;
  op[0]  = w[0] * a + w[1] * b + w[2] * c;
  op[HW] = w[3] * a + w[4] * b + w[5] * c;
}

// ---------------------------------------------------------------------------

extern "C" void kernel_launch(void* const* d_in, const int* in_sizes, int n_in,
                              void* d_out, int out_size, void* d_ws, size_t ws_size,
                              hipStream_t stream) {
  const float* x        = (const float*)d_in[0];
  const float* conv1_w  = (const float*)d_in[1];
  const float* conv1_b  = (const float*)d_in[2];
  const float* conv2_w  = (const float*)d_in[3];
  const float* conv2_b  = (const float*)d_in[4];
  const float* conv3_w  = (const float*)d_in[5];
  const float* conv3_b  = (const float*)d_in[6];
  const float* conv4_w  = (const float*)d_in[7];
  const float* conv4_b  = (const float*)d_in[8];
  const float* convd1_w = (const float*)d_in[9];
  const float* convd1_b = (const float*)d_in[10];
  const float* convd2_w = (const float*)d_in[11];
  const float* convd2_b = (const float*)d_in[12];
  const float* convd3_w = (const float*)d_in[13];
  const float* convd3_b = (const float*)d_in[14];
  const float* convd4_w = (const float*)d_in[15];
  const float* convd4_b = (const float*)d_in[16];
  const float* final_w  = (const float*)d_in[17];
  const float* gn1_w = (const float*)d_in[18];
  const float* gn1_b = (const float*)d_in[19];
  const float* gn2_w = (const float*)d_in[20];
  const float* gn2_b = (const float*)d_in[21];
  const float* gn3_w = (const float*)d_in[22];
  const float* gn3_b = (const float*)d_in[23];
  const float* gn4_w = (const float*)d_in[24];
  const float* gn4_b = (const float*)d_in[25];

  char* base = (char*)d_ws;
  size_t off = 0;
  auto allocB = [&](size_t bytes) { size_t o = off; off = (off + bytes + 255) & ~(size_t)255; return o; };

  size_t o_sw1  = allocB(16 * 108 * 4);
  size_t o_swd1 = allocB(12 * 144 * 4);
  size_t o_swd2 = allocB(16 * 288 * 4);
  size_t o_swf  = allocB(6 * 4);
  size_t o_pw2  = allocB((size_t)9 * 64 * 64 * 2);
  size_t o_pw3  = allocB((size_t)9 * 256 * 256 * 2);
  size_t o_pw4  = allocB((size_t)9 * 1024 * 1024 * 2);
  size_t o_pwd3 = allocB((size_t)9 * 64 * 128 * 2);
  size_t o_pwd4 = allocB((size_t)9 * 256 * 512 * 2);
  size_t o_ah   = allocB((size_t)16 * 34 * 34 * 512 * 2);
  size_t o_gnp  = allocB(4096 * 4);   // gn partials (max 2048 pairs)
  size_t o_gns  = allocB(4096 * 4);   // gn stats
  size_t o_c1 = allocB((size_t)NB * 16 * 128 * 128 * 4);
  size_t o_c2 = allocB((size_t)NB * 64 * 64 * 64 * 4);
  size_t o_c3 = allocB((size_t)NB * 256 * 32 * 32 * 4);
  size_t o_w4 = allocB((size_t)NB * 1024 * 16 * 16 * 4);
  size_t o_t1 = allocB((size_t)NB * 1024 * 16 * 16 * 4);
  size_t o_t2 = allocB((size_t)NB * 512 * 32 * 32 * 4);

  if (off > ws_size) return;

  float* c1 = (float*)(base + o_c1);
  float* c2 = (float*)(base + o_c2);
  float* c3 = (float*)(base + o_c3);
  float* w4 = (float*)(base + o_w4);
  float* t1 = (float*)(base + o_t1);
  float* t2 = (float*)(base + o_t2);
  f16* ah = (f16*)(base + o_ah);
  f16* pw2 = (f16*)(base + o_pw2);
  f16* pw3 = (f16*)(base + o_pw3);
  f16* pw4 = (f16*)(base + o_pw4);
  f16* pwd3 = (f16*)(base + o_pwd3);
  f16* pwd4 = (f16*)(base + o_pwd4);
  float* gnp = (float*)(base + o_gnp);
  float* gns = (float*)(base + o_gns);

  // ---- weight prep ----
  ws_kernel<<<16, 256, 0, stream>>>(conv1_w,  (float*)(base + o_sw1),  108);
  ws_kernel<<<12, 256, 0, stream>>>(convd1_w, (float*)(base + o_swd1), 144);
  ws_kernel<<<16, 256, 0, stream>>>(convd2_w, (float*)(base + o_swd2), 288);
  ws_kernel<<<2,  256, 0, stream>>>(final_w,  (float*)(base + o_swf),  3);
  ws_f16_kernel<<<64,   256, 0, stream>>>(conv2_w,  pw2,  576,  64,   64);
  ws_f16_kernel<<<256,  256, 0, stream>>>(conv3_w,  pw3,  2304, 256,  256);
  ws_f16_kernel<<<1024, 256, 0, stream>>>(conv4_w,  pw4,  9216, 1024, 1024);
  ws_f16_kernel<<<64,   256, 0, stream>>>(convd3_w, pwd3, 1152, 128,  64);
  ws_f16_kernel<<<256,  256, 0, stream>>>(convd4_w, pwd4, 4608, 512,  256);

  auto launch_wt = [&](const float* in, float* out, int C, int Ho, int Wo) {
    int total = NB * C * Ho * Wo;
    wt_kernel<<<(total + 255) / 256, 256, 0, stream>>>(in, out, C, Ho, Wo, total);
  };
  auto prep_nhwc = [&](const float* in, int C, int H, int W) {
    int total8 = NB * (2 * (W + 2) + 2 * H) * (C / 8);
    zero_halo_kernel<<<(total8 + 255) / 256, 256, 0, stream>>>(ah, C, H, W, total8);
    dim3 g((H * W) / 256, C / 32, NB);
    to_nhwc_pad_kernel<<<g, 256, 0, stream>>>(in, ah, C, H, W);
  };
  auto launch_cmfma = [&](const f16* w, const float* b, float* o,
                          int Cin, int Hs, int Ws, int Cout, int lr) {
    dim3 g((NB * Hs * Ws) / 128, Cout / 64);
    conv_mfma2_kernel<<<g, 256, 0, stream>>>(ah, w, b, o, Cin, Hs, Ws, Cout, Hs * Ws, lr);
  };
  auto launch_conv = [&](const float* in, const float* w, const float* b, float* out,
                         int Cin, int H, int W, int Cout, int lrelu) {
    dim3 g((W / 16) * (H / 16), Cout / 4, NB);
    conv3x3_kernel<4, 4><<<g, 256, 0, stream>>>(in, w, b, out, Cin, H, W, Cout, lrelu);
  };
  auto launch_gn = [&](float* xb, const float* g, const float* b, int C, int HW, int G) {
    int SPLIT = 2048 / (G * NB);            // G in {2,8,32,128} -> SPLIT {64,16,4,1}
    if (SPLIT < 1) SPLIT = 1;
    int len = (C / G) * HW;
    dim3 gs(G * SPLIT, NB);
    gn_stats_kernel<<<gs, 256, 0, stream>>>(xb, gnp, C, HW, G, SPLIT);
    int tot = NB * G;
    gn_combine_kernel<<<(tot + 255) / 256, 256, 0, stream>>>(gnp, gns, SPLIT, len, tot);
    int total4 = (NB * C * HW) >> 2;
    gn_apply_kernel<<<(total4 + 255) / 256, 256, 0, stream>>>(xb, gns, g, b, C, HW, G, total4);
  };
  auto launch_iwt = [&](const float* v, float* out, int C, int H, int W, int c_off, int Ctot) {
    int total = NB * C * H * W;
    iwt_kernel<<<(total + 255) / 256, 256, 0, stream>>>(v, out, C, H, W, c_off, Ctot, total);
  };
  auto launch_copycat = [&](const float* src, float* dst, int C, int HW, int Ctot) {
    int total = NB * C * HW;
    copycat_kernel<<<(total + 255) / 256, 256, 0, stream>>>(src, dst, C, HW, Ctot, total);
  };

  // ---- encoder ----
  launch_wt(x, t1, 3, 128, 128);                                   // w1 (16,12,128,128)
  launch_conv(t1, (float*)(base + o_sw1), conv1_b, c1, 12, 128, 128, 16, 1);
  launch_gn(c1, gn1_w, gn1_b, 16, 128 * 128, 2);

  launch_wt(c1, t1, 16, 64, 64);                                   // w2 (16,64,64,64)
  prep_nhwc(t1, 64, 64, 64);
  launch_cmfma(pw2, conv2_b, c2, 64, 64, 64, 64, 1);               // c2
  launch_gn(c2, gn2_w, gn2_b, 64, 64 * 64, 8);

  launch_wt(c2, t1, 64, 32, 32);                                   // w3 (16,256,32,32)
  prep_nhwc(t1, 256, 32, 32);
  launch_cmfma(pw3, conv3_b, c3, 256, 32, 32, 256, 1);             // c3
  launch_gn(c3, gn3_w, gn3_b, 256, 32 * 32, 32);

  launch_wt(c3, w4, 256, 16, 16);                                  // w4 (16,1024,16,16)

  prep_nhwc(w4, 1024, 16, 16);
  launch_cmfma(pw4, conv4_b, t1, 1024, 16, 16, 1024, 1);           // c4 -> t1
  launch_gn(t1, gn4_w, gn4_b, 1024, 16 * 16, 128);
  prep_nhwc(t1, 1024, 16, 16);
  launch_cmfma(pw4, conv4_b, t2, 1024, 16, 16, 1024, 1);           // c5 -> t2
  launch_gn(t2, gn4_w, gn4_b, 1024, 16 * 16, 128);
  prep_nhwc(t2, 1024, 16, 16);
  launch_cmfma(pw4, conv4_b, t1, 1024, 16, 16, 1024, 0);           // c6 -> t1

  {  // ic4 = lrelu(c6 + w4) in t1
    int total = NB * 1024 * 16 * 16;
    addlrelu_kernel<<<(total + 255) / 256, 256, 0, stream>>>(t1, w4, total);
  }

  // ---- decoder ----
  launch_copycat(c3, t2, 256, 32 * 32, 512);                       // iw4 -> t2
  launch_iwt(t1, t2, 256, 16, 16, 256, 512);
  prep_nhwc(t2, 512, 32, 32);
  launch_cmfma(pwd4, convd4_b, t1, 512, 32, 32, 256, 1);           // ic3 -> t1
  launch_gn(t1, gn3_w, gn3_b, 256, 32 * 32, 32);

  launch_copycat(c2, t2, 64, 64 * 64, 128);                        // iw3 -> t2
  launch_iwt(t1, t2, 64, 32, 32, 64, 128);
  prep_nhwc(t2, 128, 64, 64);
  launch_cmfma(pwd3, convd3_b, t1, 128, 64, 64, 64, 1);            // ic2 -> t1
  launch_gn(t1, gn2_w, gn2_b, 64, 64 * 64, 8);

  launch_copycat(c1, t2, 16, 128 * 128, 32);                       // iw2 -> t2
  launch_iwt(t1, t2, 16, 64, 64, 16, 32);
  launch_conv(t2, (float*)(base + o_swd2), convd2_b, t1, 32, 128, 128, 16, 1);  // ic1
  launch_gn(t1, gn1_w, gn1_b, 16, 128 * 128, 2);

  launch_conv(t1, (float*)(base + o_swd1), convd1_b, t2, 16, 128, 128, 12, 1);  // iw1

  launch_iwt(t2, t1, 3, 128, 128, 0, 3);                           // iwt(iw1) (16,3,256,256)

  {  // final 1x1
    int total = NB * 256 * 256;
    final_conv_kernel<<<(total + 255) / 256, 256, 0, stream>>>(t1, (float*)(base + o_swf),
                                                               (float*)d_out, 256 * 256, total);
  }
}